// Round 3
// baseline (598.267 us; speedup 1.0000x reference)
//
#include <hip/hip_runtime.h>

// CCQC quantum-circuit classifier, fused single-kernel state-vector sim.
// State layout: one wave (64 lanes) per batch element; amplitude index
// j = k*64 + lane (k in [0,16)). Wire i (MSB-first) <-> bit b = 9-i of j.
// b in [6,9] -> k-bit (in-lane register pair); b in [0,5] -> lane bit (shfl_xor).
// R1: hoisted per-k selects to per-gate lane-invariant coefficients; U0 fused fwd.
// R2: amplitudes packed (re,im) in VGPR pairs; complex MAC = 2 x v_pk_fma_f32
//     (VOP3P dual-f32) via inline asm with op_sel broadcast/swap + neg_lo.

namespace {

typedef float f32x2 __attribute__((ext_vector_type(2)));

// d = (cc.lo*v.lo, cc.lo*v.hi)   -- start of complex MAC: cc.re * (v.re, v.im)
__device__ __forceinline__ f32x2 pk_mul_lo(f32x2 cc, f32x2 v) {
  f32x2 d;
  asm("v_pk_mul_f32 %0, %1, %2 op_sel:[0,0] op_sel_hi:[0,1]"
      : "=v"(d) : "v"(cc), "v"(v));
  return d;
}
// d += (cc.lo*v.lo, cc.lo*v.hi)
__device__ __forceinline__ void pk_fma_lo(f32x2& d, f32x2 cc, f32x2 v) {
  asm("v_pk_fma_f32 %0, %1, %2, %0 op_sel:[0,0,0] op_sel_hi:[0,1,1]"
      : "+v"(d) : "v"(cc), "v"(v));
}
// d += (-cc.hi*v.hi, cc.hi*v.lo) -- completes complex multiply by cc
__device__ __forceinline__ void pk_fma_hi(f32x2& d, f32x2 cc, f32x2 v) {
  asm("v_pk_fma_f32 %0, %1, %2, %0 op_sel:[1,1,0] op_sel_hi:[1,0,1] neg_lo:[1,0,0]"
      : "+v"(d) : "v"(cc), "v"(v));
}

// d = cc (*) v  (complex product), 2 instructions
__device__ __forceinline__ f32x2 cmul2(f32x2 cc, f32x2 v) {
  f32x2 d = pk_mul_lo(cc, v);
  pk_fma_hi(d, cc, v);
  return d;
}
// d += cc (*) v, 2 instructions
__device__ __forceinline__ void cmac2(f32x2& d, f32x2 cc, f32x2 v) {
  pk_fma_lo(d, cc, v);
  pk_fma_hi(d, cc, v);
}

__device__ __forceinline__ f32x2 shfl_xor2(f32x2 v, int lm) {
  f32x2 r;
  r.x = __shfl_xor(v.x, lm, 64);
  r.y = __shfl_xor(v.y, lm, 64);
  return r;
}
__device__ __forceinline__ f32x2 sel2(bool c, f32x2 a, f32x2 b) {
  f32x2 r; r.x = c ? a.x : b.x; r.y = c ? a.y : b.y; return r;
}

struct c2 { float r, i; };
struct m2c { c2 a00, a01, a10, a11; };

__device__ __forceinline__ c2 cmul(c2 x, c2 y) { return {x.r*y.r - x.i*y.i, x.r*y.i + x.i*y.r}; }
__device__ __forceinline__ c2 cadd(c2 x, c2 y) { return {x.r + y.r, x.i + y.i}; }
__device__ __forceinline__ m2c mmul(m2c A, m2c B) {
  m2c C;
  C.a00 = cadd(cmul(A.a00, B.a00), cmul(A.a01, B.a10));
  C.a01 = cadd(cmul(A.a00, B.a01), cmul(A.a01, B.a11));
  C.a10 = cadd(cmul(A.a10, B.a00), cmul(A.a11, B.a10));
  C.a11 = cadd(cmul(A.a10, B.a01), cmul(A.a11, B.a11));
  return C;
}
__device__ __forceinline__ m2c mrx(float t) {
  float c = cosf(0.5f * t), s = sinf(0.5f * t);
  return { {c, 0.f}, {0.f, -s}, {0.f, -s}, {c, 0.f} };
}
__device__ __forceinline__ m2c mrz(float t) {
  float c = cosf(0.5f * t), s = sinf(0.5f * t);
  return { {c, -s}, {0.f, 0.f}, {0.f, 0.f}, {c, s} };
}

// Fused gate matrices -> ws. Layout: per layer d (21 matrices of 8 floats):
//   [0..9]  U1[i]  = RX(w[d,i,2]) * RZ(w[d,i,1]) * RX(w[d,i,0]); for i==0,d>0
//                    additionally right-multiplied by U0[d-1] (wire-0 fusion)
//   [10..19] CU[i] = RX(w[d,i,4]) * RZ(w[d,i,3])   (ctrl = (i+r)%10)
//   [20]    U0     = RZ(w2[d]) * RX(w1[d])          (applied only for d==4)
__global__ void make_mats(const float* __restrict__ w, const float* __restrict__ w1,
                          const float* __restrict__ w2, float* __restrict__ mats) {
  int t = threadIdx.x;
  m2c U{}; int idx = -1;
  if (t < 50) {
    int d = t / 10, i = t % 10;
    const float* p = w + (d * 10 + i) * 5;
    U = mmul(mrx(p[2]), mmul(mrz(p[1]), mrx(p[0])));
    if (i == 0 && d > 0) {
      m2c U0 = mmul(mrz(w2[d - 1]), mrx(w1[d - 1]));
      U = mmul(U, U0);   // state <- U1 * (U0 * state)
    }
    idx = d * 21 + i;
  } else if (t < 100) {
    int s = t - 50; int d = s / 10, i = s % 10;
    const float* p = w + (d * 10 + i) * 5;
    U = mmul(mrx(p[4]), mrz(p[3]));
    idx = d * 21 + 10 + i;
  } else if (t < 105) {
    int d = t - 100;
    U = mmul(mrz(w2[d]), mrx(w1[d]));
    idx = d * 21 + 20;
  }
  if (idx >= 0) {
    float* o = mats + idx * 8;
    o[0] = U.a00.r; o[1] = U.a00.i; o[2] = U.a01.r; o[3] = U.a01.i;
    o[4] = U.a10.r; o[5] = U.a10.i; o[6] = U.a11.r; o[7] = U.a11.i;
  }
}

struct Mat2 { f32x2 u00, u01, u10, u11; };

__device__ __forceinline__ Mat2 ldmat(const float* __restrict__ mats, int idx) {
  const float4* p = reinterpret_cast<const float4*>(mats + idx * 8);
  float4 a = p[0], b = p[1];
  Mat2 m;
  m.u00 = f32x2{a.x, a.y}; m.u01 = f32x2{a.z, a.w};
  m.u10 = f32x2{b.x, b.y}; m.u11 = f32x2{b.z, b.w};
  return m;
}

// Single-qubit gate, target bit is a k-bit (kb = b-6). 8 packed ops/pair.
__device__ __forceinline__ void ap1q_local(f32x2 (&s)[16], const int kb, const Mat2 m) {
  const int tm = 1 << kb;
  #pragma unroll
  for (int k0 = 0; k0 < 16; ++k0) {
    if (k0 & tm) continue;
    const int k1 = k0 | tm;
    const f32x2 a = s[k0], b = s[k1];
    f32x2 na = cmul2(m.u00, a); cmac2(na, m.u01, b);
    f32x2 nb = cmul2(m.u10, a); cmac2(nb, m.u11, b);
    s[k0] = na; s[k1] = nb;
  }
}

// Single-qubit gate, target bit is a lane bit. new = cA*own + cB*partner,
// cA/cB lane-invariant per gate. 4 packed ops + 2 shuffles per k.
__device__ __forceinline__ void ap1q_xlane(f32x2 (&s)[16], const int lm,
                                           const f32x2 cA, const f32x2 cB) {
  #pragma unroll
  for (int k = 0; k < 16; ++k) {
    const f32x2 p = shfl_xor2(s[k], lm);
    f32x2 d = cmul2(cA, s[k]);
    cmac2(d, cB, p);
    s[k] = d;
  }
}

// Controlled gate, target is a k-bit (kb = bt-6); ctrl bit bc (j-bit index).
__device__ __forceinline__ void apc_local(f32x2 (&s)[16], const int lane, const int bc,
                                          const int kb, Mat2 m) {
  const int tm = 1 << kb;
  if (bc >= 6) {
    const int cm = 1 << (bc - 6);
    #pragma unroll
    for (int k0 = 0; k0 < 16; ++k0) {
      if ((k0 & tm) || !(k0 & cm)) continue;
      const int k1 = k0 | tm;
      const f32x2 a = s[k0], b = s[k1];
      f32x2 na = cmul2(m.u00, a); cmac2(na, m.u01, b);
      f32x2 nb = cmul2(m.u10, a); cmac2(nb, m.u11, b);
      s[k0] = na; s[k1] = nb;
    }
  } else {
    // ctrl is a lane bit: fold control into the matrix once (M or I per lane).
    const bool cl = ((lane >> bc) & 1) != 0;
    const f32x2 one{1.f, 0.f}, zero{0.f, 0.f};
    m.u00 = sel2(cl, m.u00, one); m.u01 = sel2(cl, m.u01, zero);
    m.u10 = sel2(cl, m.u10, zero); m.u11 = sel2(cl, m.u11, one);
    ap1q_local(s, kb, m);
  }
}

// Controlled gate, target is a lane bit; ctrl bit bc.
__device__ __forceinline__ void apc_xlane(f32x2 (&s)[16], const int lane, const int bc,
                                          const int lm, const Mat2 m) {
  const bool hi = (lane & lm) != 0;
  f32x2 cA = sel2(hi, m.u11, m.u00);
  f32x2 cB = sel2(hi, m.u10, m.u01);
  if (bc >= 6) {
    const int cm = 1 << (bc - 6);
    #pragma unroll
    for (int k = 0; k < 16; ++k) {
      if (!(k & cm)) continue;   // ctrl bit lives in k: only these amps touched
      const f32x2 p = shfl_xor2(s[k], lm);
      f32x2 d = cmul2(cA, s[k]);
      cmac2(d, cB, p);
      s[k] = d;
    }
  } else {
    // ctrl is a lane bit (partner lane shares it): fold into coefficients once.
    const bool cl = ((lane >> bc) & 1) != 0;
    cA = sel2(cl, cA, f32x2{1.f, 0.f});
    cB = sel2(cl, cB, f32x2{0.f, 0.f});
    #pragma unroll
    for (int k = 0; k < 16; ++k) {
      const f32x2 p = shfl_xor2(s[k], lm);
      f32x2 d = cmul2(cA, s[k]);
      cmac2(d, cB, p);
      s[k] = d;
    }
  }
}

__global__ __launch_bounds__(256) void qsim(const float* __restrict__ x,
                                            const int* __restrict__ y,
                                            const float* __restrict__ mats,
                                            float* __restrict__ partials) {
  const int lane = threadIdx.x & 63;
  const int wave = threadIdx.x >> 6;
  const int b = blockIdx.x * 4 + wave;
  const int yv = y[b];

  f32x2 s[16];
  float ss = 0.f;
  #pragma unroll
  for (int k = 0; k < 16; ++k) {
    const int j = k * 64 + lane;
    float v = 0.f;
    if (j < 784) v = x[(size_t)b * 784 + j];
    s[k].x = v; s[k].y = 0.f; ss += v * v;
  }
  #pragma unroll
  for (int mm = 1; mm < 64; mm <<= 1) ss += __shfl_xor(ss, mm, 64);
  const float rn = rsqrtf(ss);
  #pragma unroll
  for (int k = 0; k < 16; ++k) s[k].x *= rn;

  #pragma unroll
  for (int d = 0; d < 5; ++d) {
    #pragma unroll
    for (int i = 0; i < 10; ++i) {
      const Mat2 m = ldmat(mats, d * 21 + i);
      const int bt = 9 - i;
      if (bt >= 6) {
        ap1q_local(s, bt - 6, m);
      } else {
        const bool hi = (lane & (1 << bt)) != 0;
        ap1q_xlane(s, 1 << bt, sel2(hi, m.u11, m.u00), sel2(hi, m.u10, m.u01));
      }
    }
    const int r = (d & 1) ? 3 : 1;
    #pragma unroll
    for (int i = 0; i < 10; ++i) {
      const int c = (i + r) % 10;
      const Mat2 m = ldmat(mats, d * 21 + 10 + i);
      const int bc = 9 - c, bt = 9 - i;
      if (bt >= 6) apc_local(s, lane, bc, bt - 6, m);
      else         apc_xlane(s, lane, bc, 1 << bt, m);
    }
    if (d == 4) {  // U0 for d<4 is fused into U1[d+1, 0] by make_mats
      const Mat2 m = ldmat(mats, d * 21 + 20);
      ap1q_local(s, 3, m);   // wire 0 -> j bit 9 -> k bit 3
    }
  }

  // expz for wire 0 (k bit 3) and wire 1 (k bit 2)
  float z0 = 0.f, z1 = 0.f;
  #pragma unroll
  for (int k = 0; k < 16; ++k) {
    const float p = s[k].x * s[k].x + s[k].y * s[k].y;
    z0 += (k & 8) ? -p : p;
    z1 += (k & 4) ? -p : p;
  }
  #pragma unroll
  for (int mm = 1; mm < 64; mm <<= 1) {
    z0 += __shfl_xor(z0, mm, 64);
    z1 += __shfl_xor(z1, mm, 64);
  }

  __shared__ float part[4];
  if (lane == 0) {
    const float mx = fmaxf(z0, z1);
    const float lse = mx + logf(expf(z0 - mx) + expf(z1 - mx));
    const float ly = (yv == 0) ? z0 : z1;
    part[wave] = lse - ly;
  }
  __syncthreads();
  if (threadIdx.x == 0)
    partials[blockIdx.x] = part[0] + part[1] + part[2] + part[3];
}

__global__ void reduce_mean(const float* __restrict__ part, float* __restrict__ out,
                            int n, float scale) {
  const int t = threadIdx.x;
  float s = 0.f;
  for (int i = t; i < n; i += 256) s += part[i];
  #pragma unroll
  for (int mm = 1; mm < 64; mm <<= 1) s += __shfl_xor(s, mm, 64);
  __shared__ float ws[4];
  if ((t & 63) == 0) ws[t >> 6] = s;
  __syncthreads();
  if (t == 0) out[0] = (ws[0] + ws[1] + ws[2] + ws[3]) * scale;
}

} // namespace

extern "C" void kernel_launch(void* const* d_in, const int* in_sizes, int n_in,
                              void* d_out, int out_size, void* d_ws, size_t ws_size,
                              hipStream_t stream) {
  const float* x  = (const float*)d_in[0];
  const int*   y  = (const int*)d_in[1];
  const float* w  = (const float*)d_in[2];
  const float* w1 = (const float*)d_in[3];
  const float* w2 = (const float*)d_in[4];
  float* out = (float*)d_out;

  const int B = in_sizes[0] / 784;      // 8192
  const int nblocks = B / 4;            // 4 waves (batch elems) per 256-thread block

  float* mats     = (float*)d_ws;       // 840 floats
  float* partials = (float*)d_ws + 1024;

  make_mats<<<1, 128, 0, stream>>>(w, w1, w2, mats);
  qsim<<<nblocks, 256, 0, stream>>>(x, y, mats, partials);
  reduce_mean<<<1, 256, 0, stream>>>(partials, out, nblocks, 1.0f / (float)B);
}

// Round 4
// 183.806 us; speedup vs baseline: 3.2549x; 3.2549x over previous
//
#include <hip/hip_runtime.h>

// CCQC quantum-circuit classifier, fused single-kernel state-vector sim.
// State layout: one wave (64 lanes) per batch element; amplitude index
// j = k*64 + lane (k in [0,16)). Wire i (MSB-first) <-> bit b = 9-i of j.
// b in [6,9] -> k-bit (in-lane register pair); b in [0,5] -> lane bit (shfl_xor).
// R1: hoisted per-k selects to lane-invariant coefficients; U0 fused forward.
// R3(R4): packed complex math via COMPILER-NATIVE f32x2 vector ops (VOP3P
//   v_pk_fma_f32), not inline asm (R3's asm caused a 256-VGPR scratch spill).
//   Coefficients pre-expanded in make_mats: per entry {re,re} and {-im,im},
//   so a complex MAC is cr2*v + ci2*swap(v) (2 packed FMAs).

namespace {

typedef float f32x2 __attribute__((ext_vector_type(2)));

__device__ __forceinline__ f32x2 swap2(f32x2 v) {
  return __builtin_shufflevector(v, v, 1, 0);
}
__device__ __forceinline__ f32x2 shfl_xor2(f32x2 v, int lm) {
  f32x2 r;
  r.x = __shfl_xor(v.x, lm, 64);
  r.y = __shfl_xor(v.y, lm, 64);
  return r;
}
__device__ __forceinline__ f32x2 sel2(bool c, f32x2 a, f32x2 b) {
  f32x2 r; r.x = c ? a.x : b.x; r.y = c ? a.y : b.y; return r;
}

struct c2 { float r, i; };
struct m2c { c2 a00, a01, a10, a11; };

__device__ __forceinline__ c2 cmul(c2 x, c2 y) { return {x.r*y.r - x.i*y.i, x.r*y.i + x.i*y.r}; }
__device__ __forceinline__ c2 cadd(c2 x, c2 y) { return {x.r + y.r, x.i + y.i}; }
__device__ __forceinline__ m2c mmul(m2c A, m2c B) {
  m2c C;
  C.a00 = cadd(cmul(A.a00, B.a00), cmul(A.a01, B.a10));
  C.a01 = cadd(cmul(A.a00, B.a01), cmul(A.a01, B.a11));
  C.a10 = cadd(cmul(A.a10, B.a00), cmul(A.a11, B.a10));
  C.a11 = cadd(cmul(A.a10, B.a01), cmul(A.a11, B.a11));
  return C;
}
__device__ __forceinline__ m2c mrx(float t) {
  float c = cosf(0.5f * t), s = sinf(0.5f * t);
  return { {c, 0.f}, {0.f, -s}, {0.f, -s}, {c, 0.f} };
}
__device__ __forceinline__ m2c mrz(float t) {
  float c = cosf(0.5f * t), s = sinf(0.5f * t);
  return { {c, -s}, {0.f, 0.f}, {0.f, 0.f}, {c, s} };
}

// Fused gate matrices -> ws, pre-expanded for packed math.
// Per matrix 16 floats: for each entry e of {00,01,10,11}:
//   {e.re, e.re, -e.im, e.im}
// Per layer d: [0..9] U1[i] (i==0,d>0 absorbs U0[d-1]); [10..19] CU[i]; [20] U0.
__global__ void make_mats(const float* __restrict__ w, const float* __restrict__ w1,
                          const float* __restrict__ w2, float* __restrict__ mats) {
  int t = threadIdx.x;
  m2c U{}; int idx = -1;
  if (t < 50) {
    int d = t / 10, i = t % 10;
    const float* p = w + (d * 10 + i) * 5;
    U = mmul(mrx(p[2]), mmul(mrz(p[1]), mrx(p[0])));
    if (i == 0 && d > 0) {
      m2c U0 = mmul(mrz(w2[d - 1]), mrx(w1[d - 1]));
      U = mmul(U, U0);   // state <- U1 * (U0 * state)
    }
    idx = d * 21 + i;
  } else if (t < 100) {
    int s = t - 50; int d = s / 10, i = s % 10;
    const float* p = w + (d * 10 + i) * 5;
    U = mmul(mrx(p[4]), mrz(p[3]));
    idx = d * 21 + 10 + i;
  } else if (t < 105) {
    int d = t - 100;
    U = mmul(mrz(w2[d]), mrx(w1[d]));
    idx = d * 21 + 20;
  }
  if (idx >= 0) {
    float* o = mats + idx * 16;
    const c2 e[4] = {U.a00, U.a01, U.a10, U.a11};
    #pragma unroll
    for (int q = 0; q < 4; ++q) {
      o[q*4 + 0] = e[q].r; o[q*4 + 1] = e[q].r;
      o[q*4 + 2] = -e[q].i; o[q*4 + 3] = e[q].i;
    }
  }
}

// Packed-coefficient matrix: per entry, r2 = {re,re}, i2 = {-im,im}.
struct MatP { f32x2 u00r, u00i, u01r, u01i, u10r, u10i, u11r, u11i; };

__device__ __forceinline__ MatP ldmat(const float* __restrict__ mats, int idx) {
  const float4* p = reinterpret_cast<const float4*>(mats + idx * 16);
  float4 a = p[0], b = p[1], c = p[2], d = p[3];
  MatP m;
  m.u00r = f32x2{a.x, a.y}; m.u00i = f32x2{a.z, a.w};
  m.u01r = f32x2{b.x, b.y}; m.u01i = f32x2{b.z, b.w};
  m.u10r = f32x2{c.x, c.y}; m.u10i = f32x2{c.z, c.w};
  m.u11r = f32x2{d.x, d.y}; m.u11i = f32x2{d.z, d.w};
  return m;
}

// complex multiply-accumulate in packed form: acc + cr2*v + ci2*swap(v)
__device__ __forceinline__ f32x2 cmad(f32x2 acc, f32x2 cr2, f32x2 ci2, f32x2 v) {
  return acc + cr2 * v + ci2 * swap2(v);
}
__device__ __forceinline__ f32x2 cmulp(f32x2 cr2, f32x2 ci2, f32x2 v) {
  return cr2 * v + ci2 * swap2(v);
}

// Single-qubit gate, target bit is a k-bit (kb = b-6).
__device__ __forceinline__ void ap1q_local(f32x2 (&s)[16], const int kb, const MatP m) {
  const int tm = 1 << kb;
  #pragma unroll
  for (int k0 = 0; k0 < 16; ++k0) {
    if (k0 & tm) continue;
    const int k1 = k0 | tm;
    const f32x2 a = s[k0], b = s[k1];
    s[k0] = cmad(cmulp(m.u00r, m.u00i, a), m.u01r, m.u01i, b);
    s[k1] = cmad(cmulp(m.u10r, m.u10i, a), m.u11r, m.u11i, b);
  }
}

// Single-qubit gate, target bit is a lane bit. new = cA*own + cB*partner.
__device__ __forceinline__ void ap1q_xlane(f32x2 (&s)[16], const int lm,
                                           const f32x2 cAr, const f32x2 cAi,
                                           const f32x2 cBr, const f32x2 cBi) {
  #pragma unroll
  for (int k = 0; k < 16; ++k) {
    const f32x2 p = shfl_xor2(s[k], lm);
    s[k] = cmad(cmulp(cAr, cAi, s[k]), cBr, cBi, p);
  }
}

// Controlled gate, target is a k-bit (kb = bt-6); ctrl bit bc (j-bit index).
__device__ __forceinline__ void apc_local(f32x2 (&s)[16], const int lane, const int bc,
                                          const int kb, MatP m) {
  const int tm = 1 << kb;
  if (bc >= 6) {
    const int cm = 1 << (bc - 6);
    #pragma unroll
    for (int k0 = 0; k0 < 16; ++k0) {
      if ((k0 & tm) || !(k0 & cm)) continue;
      const int k1 = k0 | tm;
      const f32x2 a = s[k0], b = s[k1];
      s[k0] = cmad(cmulp(m.u00r, m.u00i, a), m.u01r, m.u01i, b);
      s[k1] = cmad(cmulp(m.u10r, m.u10i, a), m.u11r, m.u11i, b);
    }
  } else {
    // ctrl is a lane bit: fold control into the matrix once (M or I per lane).
    const bool cl = ((lane >> bc) & 1) != 0;
    const f32x2 oner{1.f, 1.f}, zero{0.f, 0.f};
    m.u00r = sel2(cl, m.u00r, oner); m.u00i = sel2(cl, m.u00i, zero);
    m.u01r = sel2(cl, m.u01r, zero); m.u01i = sel2(cl, m.u01i, zero);
    m.u10r = sel2(cl, m.u10r, zero); m.u10i = sel2(cl, m.u10i, zero);
    m.u11r = sel2(cl, m.u11r, oner); m.u11i = sel2(cl, m.u11i, zero);
    ap1q_local(s, kb, m);
  }
}

// Controlled gate, target is a lane bit; ctrl bit bc.
__device__ __forceinline__ void apc_xlane(f32x2 (&s)[16], const int lane, const int bc,
                                          const int lm, const MatP m) {
  const bool hi = (lane & lm) != 0;
  f32x2 cAr = sel2(hi, m.u11r, m.u00r), cAi = sel2(hi, m.u11i, m.u00i);
  f32x2 cBr = sel2(hi, m.u10r, m.u01r), cBi = sel2(hi, m.u10i, m.u01i);
  if (bc >= 6) {
    const int cm = 1 << (bc - 6);
    #pragma unroll
    for (int k = 0; k < 16; ++k) {
      if (!(k & cm)) continue;   // ctrl bit lives in k: only these amps touched
      const f32x2 p = shfl_xor2(s[k], lm);
      s[k] = cmad(cmulp(cAr, cAi, s[k]), cBr, cBi, p);
    }
  } else {
    // ctrl is a lane bit (partner lane shares it): fold into coefficients once.
    const bool cl = ((lane >> bc) & 1) != 0;
    const f32x2 oner{1.f, 1.f}, zero{0.f, 0.f};
    cAr = sel2(cl, cAr, oner); cAi = sel2(cl, cAi, zero);
    cBr = sel2(cl, cBr, zero); cBi = sel2(cl, cBi, zero);
    #pragma unroll
    for (int k = 0; k < 16; ++k) {
      const f32x2 p = shfl_xor2(s[k], lm);
      s[k] = cmad(cmulp(cAr, cAi, s[k]), cBr, cBi, p);
    }
  }
}

__global__ __launch_bounds__(256) void qsim(const float* __restrict__ x,
                                            const int* __restrict__ y,
                                            const float* __restrict__ mats,
                                            float* __restrict__ partials) {
  const int lane = threadIdx.x & 63;
  const int wave = threadIdx.x >> 6;
  const int b = blockIdx.x * 4 + wave;
  const int yv = y[b];

  f32x2 s[16];
  float ss = 0.f;
  #pragma unroll
  for (int k = 0; k < 16; ++k) {
    const int j = k * 64 + lane;
    float v = 0.f;
    if (j < 784) v = x[(size_t)b * 784 + j];
    s[k].x = v; s[k].y = 0.f; ss += v * v;
  }
  #pragma unroll
  for (int mm = 1; mm < 64; mm <<= 1) ss += __shfl_xor(ss, mm, 64);
  const float rn = rsqrtf(ss);
  #pragma unroll
  for (int k = 0; k < 16; ++k) s[k].x *= rn;

  #pragma unroll
  for (int d = 0; d < 5; ++d) {
    #pragma unroll
    for (int i = 0; i < 10; ++i) {
      const MatP m = ldmat(mats, d * 21 + i);
      const int bt = 9 - i;
      if (bt >= 6) {
        ap1q_local(s, bt - 6, m);
      } else {
        const bool hi = (lane & (1 << bt)) != 0;
        ap1q_xlane(s, 1 << bt,
                   sel2(hi, m.u11r, m.u00r), sel2(hi, m.u11i, m.u00i),
                   sel2(hi, m.u10r, m.u01r), sel2(hi, m.u10i, m.u01i));
      }
    }
    const int r = (d & 1) ? 3 : 1;
    #pragma unroll
    for (int i = 0; i < 10; ++i) {
      const int c = (i + r) % 10;
      const MatP m = ldmat(mats, d * 21 + 10 + i);
      const int bc = 9 - c, bt = 9 - i;
      if (bt >= 6) apc_local(s, lane, bc, bt - 6, m);
      else         apc_xlane(s, lane, bc, 1 << bt, m);
    }
    if (d == 4) {  // U0 for d<4 is fused into U1[d+1, 0] by make_mats
      const MatP m = ldmat(mats, d * 21 + 20);
      ap1q_local(s, 3, m);   // wire 0 -> j bit 9 -> k bit 3
    }
  }

  // expz for wire 0 (k bit 3) and wire 1 (k bit 2)
  float z0 = 0.f, z1 = 0.f;
  #pragma unroll
  for (int k = 0; k < 16; ++k) {
    const float p = s[k].x * s[k].x + s[k].y * s[k].y;
    z0 += (k & 8) ? -p : p;
    z1 += (k & 4) ? -p : p;
  }
  #pragma unroll
  for (int mm = 1; mm < 64; mm <<= 1) {
    z0 += __shfl_xor(z0, mm, 64);
    z1 += __shfl_xor(z1, mm, 64);
  }

  __shared__ float part[4];
  if (lane == 0) {
    const float mx = fmaxf(z0, z1);
    const float lse = mx + logf(expf(z0 - mx) + expf(z1 - mx));
    const float ly = (yv == 0) ? z0 : z1;
    part[wave] = lse - ly;
  }
  __syncthreads();
  if (threadIdx.x == 0)
    partials[blockIdx.x] = part[0] + part[1] + part[2] + part[3];
}

__global__ void reduce_mean(const float* __restrict__ part, float* __restrict__ out,
                            int n, float scale) {
  const int t = threadIdx.x;
  float s = 0.f;
  for (int i = t; i < n; i += 256) s += part[i];
  #pragma unroll
  for (int mm = 1; mm < 64; mm <<= 1) s += __shfl_xor(s, mm, 64);
  __shared__ float ws[4];
  if ((t & 63) == 0) ws[t >> 6] = s;
  __syncthreads();
  if (t == 0) out[0] = (ws[0] + ws[1] + ws[2] + ws[3]) * scale;
}

} // namespace

extern "C" void kernel_launch(void* const* d_in, const int* in_sizes, int n_in,
                              void* d_out, int out_size, void* d_ws, size_t ws_size,
                              hipStream_t stream) {
  const float* x  = (const float*)d_in[0];
  const int*   y  = (const int*)d_in[1];
  const float* w  = (const float*)d_in[2];
  const float* w1 = (const float*)d_in[3];
  const float* w2 = (const float*)d_in[4];
  float* out = (float*)d_out;

  const int B = in_sizes[0] / 784;      // 8192
  const int nblocks = B / 4;            // 4 waves (batch elems) per 256-thread block

  float* mats     = (float*)d_ws;       // 105 * 16 = 1680 floats
  float* partials = (float*)d_ws + 2048;

  make_mats<<<1, 128, 0, stream>>>(w, w1, w2, mats);
  qsim<<<nblocks, 256, 0, stream>>>(x, y, mats, partials);
  reduce_mean<<<1, 256, 0, stream>>>(partials, out, nblocks, 1.0f / (float)B);
}

// Round 5
// 172.942 us; speedup vs baseline: 3.4593x; 1.0628x over previous
//
#include <hip/hip_runtime.h>

// CCQC classifier, GEMM formulation.
// The circuit is input-independent: psi_b = U x_b with U a fixed 1024x1024
// unitary. Pipeline:
//   1. make_mats: fuse rotations into 105 2x2 gate matrices (packed form).
//   2. build_W:  1024 waves run the REVERSED ADJOINT circuit on basis states,
//      giving rows of U directly: Wt[n][k] = Re U[n][k], Wt[1024+n][k] = Im.
//      (coalesced row-major fp16 writes, no transpose needed)
//   3. xconv:    X fp32 (8192x784) -> fp16 padded (8192x1024). No normalize:
//      z = sum(+-p)/sum(p) is self-normalizing.
//   4. gemm_z:   fp16 MFMA GEMM (M=8192, N=2048, K=1024) with fused epilogue:
//      p = re^2+im^2 per state j; z-signs are constant per 256-col j-chunk,
//      so epilogue only needs sum(p) per (row, chunk). No psi materialized.
//   5. nll_mean: logits from chunk partials, log-softmax NLL, mean.

namespace {

typedef float f32x2 __attribute__((ext_vector_type(2)));
typedef _Float16 f16x8 __attribute__((ext_vector_type(8)));
typedef float f32x4v __attribute__((ext_vector_type(4)));

__device__ __forceinline__ f32x2 swap2(f32x2 v) {
  return __builtin_shufflevector(v, v, 1, 0);
}
__device__ __forceinline__ f32x2 shfl_xor2(f32x2 v, int lm) {
  f32x2 r;
  r.x = __shfl_xor(v.x, lm, 64);
  r.y = __shfl_xor(v.y, lm, 64);
  return r;
}
__device__ __forceinline__ f32x2 sel2(bool c, f32x2 a, f32x2 b) {
  f32x2 r; r.x = c ? a.x : b.x; r.y = c ? a.y : b.y; return r;
}

struct c2 { float r, i; };
struct m2c { c2 a00, a01, a10, a11; };

__device__ __forceinline__ c2 cmul(c2 x, c2 y) { return {x.r*y.r - x.i*y.i, x.r*y.i + x.i*y.r}; }
__device__ __forceinline__ c2 cadd(c2 x, c2 y) { return {x.r + y.r, x.i + y.i}; }
__device__ __forceinline__ m2c mmul(m2c A, m2c B) {
  m2c C;
  C.a00 = cadd(cmul(A.a00, B.a00), cmul(A.a01, B.a10));
  C.a01 = cadd(cmul(A.a00, B.a01), cmul(A.a01, B.a11));
  C.a10 = cadd(cmul(A.a10, B.a00), cmul(A.a11, B.a10));
  C.a11 = cadd(cmul(A.a10, B.a01), cmul(A.a11, B.a11));
  return C;
}
__device__ __forceinline__ m2c mrx(float t) {
  float c = cosf(0.5f * t), s = sinf(0.5f * t);
  return { {c, 0.f}, {0.f, -s}, {0.f, -s}, {c, 0.f} };
}
__device__ __forceinline__ m2c mrz(float t) {
  float c = cosf(0.5f * t), s = sinf(0.5f * t);
  return { {c, -s}, {0.f, 0.f}, {0.f, 0.f}, {c, s} };
}

// Per matrix 16 floats: for each entry e of {00,01,10,11}: {re, re, -im, im}.
// Layer d: [0..9] U1[i] (i==0,d>0 absorbs U0[d-1]); [10..19] CU[i]; [20] U0.
__global__ void make_mats(const float* __restrict__ w, const float* __restrict__ w1,
                          const float* __restrict__ w2, float* __restrict__ mats) {
  int t = threadIdx.x;
  m2c U{}; int idx = -1;
  if (t < 50) {
    int d = t / 10, i = t % 10;
    const float* p = w + (d * 10 + i) * 5;
    U = mmul(mrx(p[2]), mmul(mrz(p[1]), mrx(p[0])));
    if (i == 0 && d > 0) {
      m2c U0 = mmul(mrz(w2[d - 1]), mrx(w1[d - 1]));
      U = mmul(U, U0);
    }
    idx = d * 21 + i;
  } else if (t < 100) {
    int s = t - 50; int d = s / 10, i = s % 10;
    const float* p = w + (d * 10 + i) * 5;
    U = mmul(mrx(p[4]), mrz(p[3]));
    idx = d * 21 + 10 + i;
  } else if (t < 105) {
    int d = t - 100;
    U = mmul(mrz(w2[d]), mrx(w1[d]));
    idx = d * 21 + 20;
  }
  if (idx >= 0) {
    float* o = mats + idx * 16;
    const c2 e[4] = {U.a00, U.a01, U.a10, U.a11};
    #pragma unroll
    for (int q = 0; q < 4; ++q) {
      o[q*4 + 0] = e[q].r; o[q*4 + 1] = e[q].r;
      o[q*4 + 2] = -e[q].i; o[q*4 + 3] = e[q].i;
    }
  }
}

struct MatP { f32x2 u00r, u00i, u01r, u01i, u10r, u10i, u11r, u11i; };

__device__ __forceinline__ MatP ldmat(const float* __restrict__ mats, int idx) {
  const float4* p = reinterpret_cast<const float4*>(mats + idx * 16);
  float4 a = p[0], b = p[1], c = p[2], d = p[3];
  MatP m;
  m.u00r = f32x2{a.x, a.y}; m.u00i = f32x2{a.z, a.w};
  m.u01r = f32x2{b.x, b.y}; m.u01i = f32x2{b.z, b.w};
  m.u10r = f32x2{c.x, c.y}; m.u10i = f32x2{c.z, c.w};
  m.u11r = f32x2{d.x, d.y}; m.u11i = f32x2{d.z, d.w};
  return m;
}
// Adjoint: conj-transpose. Packed conj = negate the i-vector.
__device__ __forceinline__ MatP adjmat(const float* __restrict__ mats, int idx) {
  MatP m = ldmat(mats, idx);
  MatP r;
  r.u00r = m.u00r; r.u00i = -m.u00i;
  r.u01r = m.u10r; r.u01i = -m.u10i;
  r.u10r = m.u01r; r.u10i = -m.u01i;
  r.u11r = m.u11r; r.u11i = -m.u11i;
  return r;
}

__device__ __forceinline__ f32x2 cmad(f32x2 acc, f32x2 cr2, f32x2 ci2, f32x2 v) {
  return acc + cr2 * v + ci2 * swap2(v);
}
__device__ __forceinline__ f32x2 cmulp(f32x2 cr2, f32x2 ci2, f32x2 v) {
  return cr2 * v + ci2 * swap2(v);
}

__device__ __forceinline__ void ap1q_local(f32x2 (&s)[16], const int kb, const MatP m) {
  const int tm = 1 << kb;
  #pragma unroll
  for (int k0 = 0; k0 < 16; ++k0) {
    if (k0 & tm) continue;
    const int k1 = k0 | tm;
    const f32x2 a = s[k0], b = s[k1];
    s[k0] = cmad(cmulp(m.u00r, m.u00i, a), m.u01r, m.u01i, b);
    s[k1] = cmad(cmulp(m.u10r, m.u10i, a), m.u11r, m.u11i, b);
  }
}

__device__ __forceinline__ void ap1q_xlane(f32x2 (&s)[16], const int lm,
                                           const f32x2 cAr, const f32x2 cAi,
                                           const f32x2 cBr, const f32x2 cBi) {
  #pragma unroll
  for (int k = 0; k < 16; ++k) {
    const f32x2 p = shfl_xor2(s[k], lm);
    s[k] = cmad(cmulp(cAr, cAi, s[k]), cBr, cBi, p);
  }
}

__device__ __forceinline__ void apc_local(f32x2 (&s)[16], const int lane, const int bc,
                                          const int kb, MatP m) {
  const int tm = 1 << kb;
  if (bc >= 6) {
    const int cm = 1 << (bc - 6);
    #pragma unroll
    for (int k0 = 0; k0 < 16; ++k0) {
      if ((k0 & tm) || !(k0 & cm)) continue;
      const int k1 = k0 | tm;
      const f32x2 a = s[k0], b = s[k1];
      s[k0] = cmad(cmulp(m.u00r, m.u00i, a), m.u01r, m.u01i, b);
      s[k1] = cmad(cmulp(m.u10r, m.u10i, a), m.u11r, m.u11i, b);
    }
  } else {
    const bool cl = ((lane >> bc) & 1) != 0;
    const f32x2 oner{1.f, 1.f}, zero{0.f, 0.f};
    m.u00r = sel2(cl, m.u00r, oner); m.u00i = sel2(cl, m.u00i, zero);
    m.u01r = sel2(cl, m.u01r, zero); m.u01i = sel2(cl, m.u01i, zero);
    m.u10r = sel2(cl, m.u10r, zero); m.u10i = sel2(cl, m.u10i, zero);
    m.u11r = sel2(cl, m.u11r, oner); m.u11i = sel2(cl, m.u11i, zero);
    ap1q_local(s, kb, m);
  }
}

__device__ __forceinline__ void apc_xlane(f32x2 (&s)[16], const int lane, const int bc,
                                          const int lm, const MatP m) {
  const bool hi = (lane & lm) != 0;
  f32x2 cAr = sel2(hi, m.u11r, m.u00r), cAi = sel2(hi, m.u11i, m.u00i);
  f32x2 cBr = sel2(hi, m.u10r, m.u01r), cBi = sel2(hi, m.u10i, m.u01i);
  if (bc >= 6) {
    const int cm = 1 << (bc - 6);
    #pragma unroll
    for (int k = 0; k < 16; ++k) {
      if (!(k & cm)) continue;
      const f32x2 p = shfl_xor2(s[k], lm);
      s[k] = cmad(cmulp(cAr, cAi, s[k]), cBr, cBi, p);
    }
  } else {
    const bool cl = ((lane >> bc) & 1) != 0;
    const f32x2 oner{1.f, 1.f}, zero{0.f, 0.f};
    cAr = sel2(cl, cAr, oner); cAi = sel2(cl, cAi, zero);
    cBr = sel2(cl, cBr, zero); cBi = sel2(cl, cBi, zero);
    #pragma unroll
    for (int k = 0; k < 16; ++k) {
      const f32x2 p = shfl_xor2(s[k], lm);
      s[k] = cmad(cmulp(cAr, cAi, s[k]), cBr, cBi, p);
    }
  }
}

// Row n of U via reversed-adjoint circuit on basis state e_n.
// Wt[n][k] = Re U[n][k]; Wt[1024+n][k] = Im U[n][k].
__global__ __launch_bounds__(256) void build_W(const float* __restrict__ mats,
                                               _Float16* __restrict__ Wt) {
  const int lane = threadIdx.x & 63;
  const int wave = threadIdx.x >> 6;
  const int n = blockIdx.x * 4 + wave;

  f32x2 s[16];
  const int kn = n >> 6, ln = n & 63;
  #pragma unroll
  for (int k = 0; k < 16; ++k) {
    s[k].x = (k == kn && lane == ln) ? 1.f : 0.f;
    s[k].y = 0.f;
  }

  #pragma unroll
  for (int dd = 0; dd < 5; ++dd) {
    const int d = 4 - dd;
    if (d == 4) ap1q_local(s, 3, adjmat(mats, d * 21 + 20));
    const int r = (d & 1) ? 3 : 1;
    #pragma unroll
    for (int ii = 0; ii < 10; ++ii) {
      const int i = 9 - ii;
      const int c = (i + r) % 10;
      const MatP m = adjmat(mats, d * 21 + 10 + i);
      const int bc = 9 - c, bt = 9 - i;
      if (bt >= 6) apc_local(s, lane, bc, bt - 6, m);
      else         apc_xlane(s, lane, bc, 1 << bt, m);
    }
    #pragma unroll
    for (int ii = 0; ii < 10; ++ii) {
      const int i = 9 - ii;
      const MatP m = adjmat(mats, d * 21 + i);
      const int bt = 9 - i;
      if (bt >= 6) {
        ap1q_local(s, bt - 6, m);
      } else {
        const bool hi = (lane & (1 << bt)) != 0;
        ap1q_xlane(s, 1 << bt,
                   sel2(hi, m.u11r, m.u00r), sel2(hi, m.u11i, m.u00i),
                   sel2(hi, m.u10r, m.u01r), sel2(hi, m.u10i, m.u01i));
      }
    }
  }
  // psi = U^dagger e_n => psi_k = conj(U[n][k]): Re = psi.x, Im = -psi.y.
  #pragma unroll
  for (int k = 0; k < 16; ++k) {
    const int kk = k * 64 + lane;
    Wt[(size_t)n * 1024 + kk] = (_Float16)s[k].x;
    Wt[(size_t)(1024 + n) * 1024 + kk] = (_Float16)(-s[k].y);
  }
}

// X fp32 (B x 784) -> fp16 (B x 1024), zero-padded. 784 = 98*8.
__global__ __launch_bounds__(256) void xconv(const float* __restrict__ x,
                                             _Float16* __restrict__ Xh) {
  const int t = blockIdx.x * 256 + threadIdx.x;
  const int b = t >> 7;
  const int j = (t & 127) * 8;
  f16x8 o;
  if (j < 784) {
    const float4* p = reinterpret_cast<const float4*>(x + (size_t)b * 784 + j);
    const float4 v0 = p[0], v1 = p[1];
    o[0] = (_Float16)v0.x; o[1] = (_Float16)v0.y;
    o[2] = (_Float16)v0.z; o[3] = (_Float16)v0.w;
    o[4] = (_Float16)v1.x; o[5] = (_Float16)v1.y;
    o[6] = (_Float16)v1.z; o[7] = (_Float16)v1.w;
  } else {
    #pragma unroll
    for (int q = 0; q < 8; ++q) o[q] = (_Float16)0.f;
  }
  *reinterpret_cast<f16x8*>(Xh + (size_t)b * 1024 + j) = o;
}

// C[b][n] = sum_k Xh[b][k] * Wt[n][k]; fused epilogue: per 256-col j-chunk,
// P[row] = sum_{j in chunk} (re^2 + im^2). Block: 128 rows x one j-chunk.
// 8 waves = 2(M) x 4(N); wave tile 64 rows x 64 j (re frags f0..3, im f4..7).
__global__ __launch_bounds__(512) void gemm_z(const _Float16* __restrict__ Xh,
                                              const _Float16* __restrict__ Wt,
                                              float* __restrict__ part, int B) {
  const int lane = threadIdx.x & 63;
  const int wv = threadIdx.x >> 6;
  const int wm = wv >> 2, wn = wv & 3;
  const int jc = blockIdx.y;
  const int row0 = blockIdx.x * 128 + wm * 64;
  const int j0 = jc * 256 + wn * 64;

  const int lr = lane & 15;
  const int lk = (lane >> 4) * 8;

  f32x4v acc[4][8];
  #pragma unroll
  for (int m = 0; m < 4; ++m)
    #pragma unroll
    for (int f = 0; f < 8; ++f) acc[m][f] = f32x4v{0.f, 0.f, 0.f, 0.f};

  const _Float16* xbase = Xh + (size_t)(row0 + lr) * 1024 + lk;

  #pragma unroll 2
  for (int kk = 0; kk < 32; ++kk) {
    const int k0 = kk * 32;
    f16x8 a[4], b[8];
    #pragma unroll
    for (int m = 0; m < 4; ++m)
      a[m] = *reinterpret_cast<const f16x8*>(xbase + (size_t)m * 16 * 1024 + k0);
    #pragma unroll
    for (int f = 0; f < 8; ++f) {
      const int n = (f < 4) ? (j0 + f * 16 + lr) : (1024 + j0 + (f - 4) * 16 + lr);
      b[f] = *reinterpret_cast<const f16x8*>(Wt + (size_t)n * 1024 + k0 + lk);
    }
    #pragma unroll
    for (int m = 0; m < 4; ++m)
      #pragma unroll
      for (int f = 0; f < 8; ++f)
        acc[m][f] = __builtin_amdgcn_mfma_f32_16x16x32_f16(a[m], b[f], acc[m][f], 0, 0, 0);
  }

  // p = re^2 + im^2 summed over the wave's 64 j; reduce across 16 cols (lanes).
  #pragma unroll
  for (int m = 0; m < 4; ++m) {
    f32x4v p = f32x4v{0.f, 0.f, 0.f, 0.f};
    #pragma unroll
    for (int f = 0; f < 4; ++f)
      p += acc[m][f] * acc[m][f] + acc[m][f + 4] * acc[m][f + 4];
    #pragma unroll
    for (int msk = 1; msk < 16; msk <<= 1) {
      p.x += __shfl_xor(p.x, msk, 64);
      p.y += __shfl_xor(p.y, msk, 64);
      p.z += __shfl_xor(p.z, msk, 64);
      p.w += __shfl_xor(p.w, msk, 64);
    }
    if (lr == 0) {
      const int rbase = row0 + m * 16 + (lane >> 4) * 4;
      float* dst = part + (size_t)(jc * 4 + wn) * B + rbase;
      dst[0] = p.x; dst[1] = p.y; dst[2] = p.z; dst[3] = p.w;
    }
  }
}

// logits z_q = sum_c sgn_q(c) P_c / sum_c P_c; NLL; mean over batch.
__global__ __launch_bounds__(1024) void nll_mean(const float* __restrict__ part,
                                                 const int* __restrict__ y,
                                                 float* __restrict__ out, int B) {
  const int t = threadIdx.x;
  const int rpt = B / 1024;
  float s = 0.f;
  for (int rr = 0; rr < rpt; ++rr) {
    const int row = t + rr * 1024;
    float q0 = 0.f, q1 = 0.f, nn = 0.f;
    #pragma unroll
    for (int jc = 0; jc < 4; ++jc) {
      float P = 0.f;
      #pragma unroll
      for (int wn = 0; wn < 4; ++wn) P += part[(size_t)(jc * 4 + wn) * B + row];
      const float s0 = (jc >> 1) ? -1.f : 1.f;
      const float s1 = (jc & 1) ? -1.f : 1.f;
      q0 += s0 * P; q1 += s1 * P; nn += P;
    }
    const float z0 = q0 / nn, z1 = q1 / nn;
    const float mx = fmaxf(z0, z1);
    const float lse = mx + logf(expf(z0 - mx) + expf(z1 - mx));
    const float ly = (y[row] == 0) ? z0 : z1;
    s += lse - ly;
  }
  #pragma unroll
  for (int msk = 1; msk < 64; msk <<= 1) s += __shfl_xor(s, msk, 64);
  __shared__ float red[16];
  if ((t & 63) == 0) red[t >> 6] = s;
  __syncthreads();
  if (t == 0) {
    float tot = 0.f;
    #pragma unroll
    for (int q = 0; q < 16; ++q) tot += red[q];
    out[0] = tot / (float)B;
  }
}

} // namespace

extern "C" void kernel_launch(void* const* d_in, const int* in_sizes, int n_in,
                              void* d_out, int out_size, void* d_ws, size_t ws_size,
                              hipStream_t stream) {
  const float* x  = (const float*)d_in[0];
  const int*   y  = (const int*)d_in[1];
  const float* w  = (const float*)d_in[2];
  const float* w1 = (const float*)d_in[3];
  const float* w2 = (const float*)d_in[4];
  float* out = (float*)d_out;

  const int B = in_sizes[0] / 784;      // 8192

  char* ws = (char*)d_ws;
  float*    mats = (float*)ws;                          // 6720 B
  _Float16* Wt   = (_Float16*)(ws + 8192);              // 4 MB
  _Float16* Xh   = (_Float16*)(ws + 8192 + (size_t)2048 * 1024 * 2);
  float*    part = (float*)(ws + 8192 + (size_t)2048 * 1024 * 2 + (size_t)B * 1024 * 2);

  make_mats<<<1, 128, 0, stream>>>(w, w1, w2, mats);
  build_W<<<256, 256, 0, stream>>>(mats, Wt);
  xconv<<<(B * 128) / 256, 256, 0, stream>>>(x, Xh);
  gemm_z<<<dim3(B / 128, 4), 512, 0, stream>>>(Xh, Wt, part, B);
  nll_mean<<<1, 1024, 0, stream>>>(part, y, out, B);
}

// Round 6
// 137.827 us; speedup vs baseline: 4.3407x; 1.2548x over previous
//
#include <hip/hip_runtime.h>

// CCQC classifier, GEMM formulation. R6: LDS-staged MFMA GEMM (m97 structure).
//   1. make_mats: fuse rotations into 105 2x2 gate matrices (packed form).
//   2. build_W:  1024 waves run the REVERSED ADJOINT circuit on basis states
//      -> rows of U. Wt INTERLEAVED: row 2j = Re U[j][:], row 2j+1 = Im U[j][:].
//   3. xconv:    X fp32 (8192x784) -> fp16 padded (8192x1024).
//   4. gemm_z:   C = Xh * Wt^T, M=8192 N=2048 K=832 (cols>=784 are zero),
//      128x128 tile, BK=64, double-buffered global_load_lds staging, fused
//      |psi|^2 epilogue -> 32 sign-uniform chunk partials (no psi stored).
//   5. nll_mean: logits from chunk partials, log-softmax NLL, mean.

namespace {

typedef float f32x2 __attribute__((ext_vector_type(2)));
typedef _Float16 f16x8 __attribute__((ext_vector_type(8)));
typedef float f32x4v __attribute__((ext_vector_type(4)));

__device__ __forceinline__ f32x2 swap2(f32x2 v) {
  return __builtin_shufflevector(v, v, 1, 0);
}
__device__ __forceinline__ f32x2 shfl_xor2(f32x2 v, int lm) {
  f32x2 r;
  r.x = __shfl_xor(v.x, lm, 64);
  r.y = __shfl_xor(v.y, lm, 64);
  return r;
}
__device__ __forceinline__ f32x2 sel2(bool c, f32x2 a, f32x2 b) {
  f32x2 r; r.x = c ? a.x : b.x; r.y = c ? a.y : b.y; return r;
}

struct c2 { float r, i; };
struct m2c { c2 a00, a01, a10, a11; };

__device__ __forceinline__ c2 cmul(c2 x, c2 y) { return {x.r*y.r - x.i*y.i, x.r*y.i + x.i*y.r}; }
__device__ __forceinline__ c2 cadd(c2 x, c2 y) { return {x.r + y.r, x.i + y.i}; }
__device__ __forceinline__ m2c mmul(m2c A, m2c B) {
  m2c C;
  C.a00 = cadd(cmul(A.a00, B.a00), cmul(A.a01, B.a10));
  C.a01 = cadd(cmul(A.a00, B.a01), cmul(A.a01, B.a11));
  C.a10 = cadd(cmul(A.a10, B.a00), cmul(A.a11, B.a10));
  C.a11 = cadd(cmul(A.a10, B.a01), cmul(A.a11, B.a11));
  return C;
}
__device__ __forceinline__ m2c mrx(float t) {
  float c = cosf(0.5f * t), s = sinf(0.5f * t);
  return { {c, 0.f}, {0.f, -s}, {0.f, -s}, {c, 0.f} };
}
__device__ __forceinline__ m2c mrz(float t) {
  float c = cosf(0.5f * t), s = sinf(0.5f * t);
  return { {c, -s}, {0.f, 0.f}, {0.f, 0.f}, {c, s} };
}

// Per matrix 16 floats: for each entry e of {00,01,10,11}: {re, re, -im, im}.
__global__ void make_mats(const float* __restrict__ w, const float* __restrict__ w1,
                          const float* __restrict__ w2, float* __restrict__ mats) {
  int t = threadIdx.x;
  m2c U{}; int idx = -1;
  if (t < 50) {
    int d = t / 10, i = t % 10;
    const float* p = w + (d * 10 + i) * 5;
    U = mmul(mrx(p[2]), mmul(mrz(p[1]), mrx(p[0])));
    if (i == 0 && d > 0) {
      m2c U0 = mmul(mrz(w2[d - 1]), mrx(w1[d - 1]));
      U = mmul(U, U0);
    }
    idx = d * 21 + i;
  } else if (t < 100) {
    int s = t - 50; int d = s / 10, i = s % 10;
    const float* p = w + (d * 10 + i) * 5;
    U = mmul(mrx(p[4]), mrz(p[3]));
    idx = d * 21 + 10 + i;
  } else if (t < 105) {
    int d = t - 100;
    U = mmul(mrz(w2[d]), mrx(w1[d]));
    idx = d * 21 + 20;
  }
  if (idx >= 0) {
    float* o = mats + idx * 16;
    const c2 e[4] = {U.a00, U.a01, U.a10, U.a11};
    #pragma unroll
    for (int q = 0; q < 4; ++q) {
      o[q*4 + 0] = e[q].r; o[q*4 + 1] = e[q].r;
      o[q*4 + 2] = -e[q].i; o[q*4 + 3] = e[q].i;
    }
  }
}

struct MatP { f32x2 u00r, u00i, u01r, u01i, u10r, u10i, u11r, u11i; };

__device__ __forceinline__ MatP ldmat(const float* __restrict__ mats, int idx) {
  const float4* p = reinterpret_cast<const float4*>(mats + idx * 16);
  float4 a = p[0], b = p[1], c = p[2], d = p[3];
  MatP m;
  m.u00r = f32x2{a.x, a.y}; m.u00i = f32x2{a.z, a.w};
  m.u01r = f32x2{b.x, b.y}; m.u01i = f32x2{b.z, b.w};
  m.u10r = f32x2{c.x, c.y}; m.u10i = f32x2{c.z, c.w};
  m.u11r = f32x2{d.x, d.y}; m.u11i = f32x2{d.z, d.w};
  return m;
}
__device__ __forceinline__ MatP adjmat(const float* __restrict__ mats, int idx) {
  MatP m = ldmat(mats, idx);
  MatP r;
  r.u00r = m.u00r; r.u00i = -m.u00i;
  r.u01r = m.u10r; r.u01i = -m.u10i;
  r.u10r = m.u01r; r.u10i = -m.u01i;
  r.u11r = m.u11r; r.u11i = -m.u11i;
  return r;
}

__device__ __forceinline__ f32x2 cmad(f32x2 acc, f32x2 cr2, f32x2 ci2, f32x2 v) {
  return acc + cr2 * v + ci2 * swap2(v);
}
__device__ __forceinline__ f32x2 cmulp(f32x2 cr2, f32x2 ci2, f32x2 v) {
  return cr2 * v + ci2 * swap2(v);
}

__device__ __forceinline__ void ap1q_local(f32x2 (&s)[16], const int kb, const MatP m) {
  const int tm = 1 << kb;
  #pragma unroll
  for (int k0 = 0; k0 < 16; ++k0) {
    if (k0 & tm) continue;
    const int k1 = k0 | tm;
    const f32x2 a = s[k0], b = s[k1];
    s[k0] = cmad(cmulp(m.u00r, m.u00i, a), m.u01r, m.u01i, b);
    s[k1] = cmad(cmulp(m.u10r, m.u10i, a), m.u11r, m.u11i, b);
  }
}

__device__ __forceinline__ void ap1q_xlane(f32x2 (&s)[16], const int lm,
                                           const f32x2 cAr, const f32x2 cAi,
                                           const f32x2 cBr, const f32x2 cBi) {
  #pragma unroll
  for (int k = 0; k < 16; ++k) {
    const f32x2 p = shfl_xor2(s[k], lm);
    s[k] = cmad(cmulp(cAr, cAi, s[k]), cBr, cBi, p);
  }
}

__device__ __forceinline__ void apc_local(f32x2 (&s)[16], const int lane, const int bc,
                                          const int kb, MatP m) {
  const int tm = 1 << kb;
  if (bc >= 6) {
    const int cm = 1 << (bc - 6);
    #pragma unroll
    for (int k0 = 0; k0 < 16; ++k0) {
      if ((k0 & tm) || !(k0 & cm)) continue;
      const int k1 = k0 | tm;
      const f32x2 a = s[k0], b = s[k1];
      s[k0] = cmad(cmulp(m.u00r, m.u00i, a), m.u01r, m.u01i, b);
      s[k1] = cmad(cmulp(m.u10r, m.u10i, a), m.u11r, m.u11i, b);
    }
  } else {
    const bool cl = ((lane >> bc) & 1) != 0;
    const f32x2 oner{1.f, 1.f}, zero{0.f, 0.f};
    m.u00r = sel2(cl, m.u00r, oner); m.u00i = sel2(cl, m.u00i, zero);
    m.u01r = sel2(cl, m.u01r, zero); m.u01i = sel2(cl, m.u01i, zero);
    m.u10r = sel2(cl, m.u10r, zero); m.u10i = sel2(cl, m.u10i, zero);
    m.u11r = sel2(cl, m.u11r, oner); m.u11i = sel2(cl, m.u11i, zero);
    ap1q_local(s, kb, m);
  }
}

__device__ __forceinline__ void apc_xlane(f32x2 (&s)[16], const int lane, const int bc,
                                          const int lm, const MatP m) {
  const bool hi = (lane & lm) != 0;
  f32x2 cAr = sel2(hi, m.u11r, m.u00r), cAi = sel2(hi, m.u11i, m.u00i);
  f32x2 cBr = sel2(hi, m.u10r, m.u01r), cBi = sel2(hi, m.u10i, m.u01i);
  if (bc >= 6) {
    const int cm = 1 << (bc - 6);
    #pragma unroll
    for (int k = 0; k < 16; ++k) {
      if (!(k & cm)) continue;
      const f32x2 p = shfl_xor2(s[k], lm);
      s[k] = cmad(cmulp(cAr, cAi, s[k]), cBr, cBi, p);
    }
  } else {
    const bool cl = ((lane >> bc) & 1) != 0;
    const f32x2 oner{1.f, 1.f}, zero{0.f, 0.f};
    cAr = sel2(cl, cAr, oner); cAi = sel2(cl, cAi, zero);
    cBr = sel2(cl, cBr, zero); cBi = sel2(cl, cBi, zero);
    #pragma unroll
    for (int k = 0; k < 16; ++k) {
      const f32x2 p = shfl_xor2(s[k], lm);
      s[k] = cmad(cmulp(cAr, cAi, s[k]), cBr, cBi, p);
    }
  }
}

// Row n of U via reversed-adjoint circuit on basis e_n.
// Interleaved: Wt[2n][k] = Re U[n][k]; Wt[2n+1][k] = Im U[n][k].
__global__ __launch_bounds__(256) void build_W(const float* __restrict__ mats,
                                               _Float16* __restrict__ Wt) {
  const int lane = threadIdx.x & 63;
  const int wave = threadIdx.x >> 6;
  const int n = blockIdx.x * 4 + wave;

  f32x2 s[16];
  const int kn = n >> 6, ln = n & 63;
  #pragma unroll
  for (int k = 0; k < 16; ++k) {
    s[k].x = (k == kn && lane == ln) ? 1.f : 0.f;
    s[k].y = 0.f;
  }

  #pragma unroll
  for (int dd = 0; dd < 5; ++dd) {
    const int d = 4 - dd;
    if (d == 4) ap1q_local(s, 3, adjmat(mats, d * 21 + 20));
    const int r = (d & 1) ? 3 : 1;
    #pragma unroll
    for (int ii = 0; ii < 10; ++ii) {
      const int i = 9 - ii;
      const int c = (i + r) % 10;
      const MatP m = adjmat(mats, d * 21 + 10 + i);
      const int bc = 9 - c, bt = 9 - i;
      if (bt >= 6) apc_local(s, lane, bc, bt - 6, m);
      else         apc_xlane(s, lane, bc, 1 << bt, m);
    }
    #pragma unroll
    for (int ii = 0; ii < 10; ++ii) {
      const int i = 9 - ii;
      const MatP m = adjmat(mats, d * 21 + i);
      const int bt = 9 - i;
      if (bt >= 6) {
        ap1q_local(s, bt - 6, m);
      } else {
        const bool hi = (lane & (1 << bt)) != 0;
        ap1q_xlane(s, 1 << bt,
                   sel2(hi, m.u11r, m.u00r), sel2(hi, m.u11i, m.u00i),
                   sel2(hi, m.u10r, m.u01r), sel2(hi, m.u10i, m.u01i));
      }
    }
  }
  // psi = U^dagger e_n => U[n][k] = (s.x, -s.y)
  #pragma unroll
  for (int k = 0; k < 16; ++k) {
    const int kk = k * 64 + lane;
    Wt[(size_t)(2 * n) * 1024 + kk] = (_Float16)s[k].x;
    Wt[(size_t)(2 * n + 1) * 1024 + kk] = (_Float16)(-s[k].y);
  }
}

// X fp32 (B x 784) -> fp16 (B x 1024), zero-padded.
__global__ __launch_bounds__(256) void xconv(const float* __restrict__ x,
                                             _Float16* __restrict__ Xh) {
  const int t = blockIdx.x * 256 + threadIdx.x;
  const int b = t >> 7;
  const int j = (t & 127) * 8;
  f16x8 o;
  if (j < 784) {
    const float4* p = reinterpret_cast<const float4*>(x + (size_t)b * 784 + j);
    const float4 v0 = p[0], v1 = p[1];
    o[0] = (_Float16)v0.x; o[1] = (_Float16)v0.y;
    o[2] = (_Float16)v0.z; o[3] = (_Float16)v0.w;
    o[4] = (_Float16)v1.x; o[5] = (_Float16)v1.y;
    o[6] = (_Float16)v1.z; o[7] = (_Float16)v1.w;
  } else {
    #pragma unroll
    for (int q = 0; q < 8; ++q) o[q] = (_Float16)0.f;
  }
  *reinterpret_cast<f16x8*>(Xh + (size_t)b * 1024 + j) = o;
}

// ---------------- LDS-staged GEMM ----------------
// Tile 128(M) x 128(N-rows, interleaved re/im = 64 js), BK=64, 13 K-steps
// (K=832 covers the 784 nonzero cols). 4 waves = 2(M) x 2(N), 64x64 each.
#define GZ_NSTEP 13

__device__ __forceinline__ void stage_tiles(const _Float16* __restrict__ gA,
                                            const _Float16* __restrict__ gB,
                                            _Float16* sA, _Float16* sB,
                                            int k0, int wv, int lane) {
  // per tile: 128 rows x 64 f16 = 16KB = 16 chunks of 1024B (8 rows each);
  // wave wv stages chunks [wv*4, wv*4+4) of both A and B.
  const int rIn = lane >> 3;             // row within chunk
  const int colh = (lane & 7) * 8;       // f16 col offset
  #pragma unroll
  for (int c = 0; c < 4; ++c) {
    const int chunk = wv * 4 + c;
    const size_t grow = (size_t)(chunk * 8 + rIn) * 1024 + k0 + colh;
    auto* la = (__attribute__((address_space(3))) void*)(sA + chunk * 512 + lane * 8);
    __builtin_amdgcn_global_load_lds(
        (const __attribute__((address_space(1))) void*)(gA + grow), la, 16, 0, 0);
    auto* lb = (__attribute__((address_space(3))) void*)(sB + chunk * 512 + lane * 8);
    __builtin_amdgcn_global_load_lds(
        (const __attribute__((address_space(1))) void*)(gB + grow), lb, 16, 0, 0);
  }
}

__global__ __launch_bounds__(256) void gemm_z(const _Float16* __restrict__ Xh,
                                              const _Float16* __restrict__ Wt,
                                              float* __restrict__ part, int B) {
  __shared__ _Float16 smA[2][128 * 64];
  __shared__ _Float16 smB[2][128 * 64];

  const int tid = threadIdx.x;
  const int lane = tid & 63;
  const int wv = tid >> 6;
  const int wm = wv >> 1, wn = wv & 1;
  const int row0 = blockIdx.x * 128;
  const int n0 = blockIdx.y * 128;

  const _Float16* gA = Xh + (size_t)row0 * 1024;
  const _Float16* gB = Wt + (size_t)n0 * 1024;

  const int lr = lane & 15;
  const int lk = (lane >> 4) * 8;

  f32x4v acc[4][4];
  #pragma unroll
  for (int m = 0; m < 4; ++m)
    #pragma unroll
    for (int f = 0; f < 4; ++f) acc[m][f] = f32x4v{0.f, 0.f, 0.f, 0.f};

  stage_tiles(gA, gB, smA[0], smB[0], 0, wv, lane);
  __syncthreads();

  for (int t = 0; t < GZ_NSTEP; ++t) {
    const int cur = t & 1;
    if (t + 1 < GZ_NSTEP)
      stage_tiles(gA, gB, smA[cur ^ 1], smB[cur ^ 1], (t + 1) * 64, wv, lane);

    #pragma unroll
    for (int kk = 0; kk < 2; ++kk) {
      f16x8 a[4], b[4];
      #pragma unroll
      for (int m = 0; m < 4; ++m)
        a[m] = *reinterpret_cast<const f16x8*>(
            &smA[cur][(wm * 64 + m * 16 + lr) * 64 + kk * 32 + lk]);
      #pragma unroll
      for (int f = 0; f < 4; ++f)
        b[f] = *reinterpret_cast<const f16x8*>(
            &smB[cur][(wn * 64 + f * 16 + lr) * 64 + kk * 32 + lk]);
      #pragma unroll
      for (int m = 0; m < 4; ++m)
        #pragma unroll
        for (int f = 0; f < 4; ++f)
          acc[m][f] = __builtin_amdgcn_mfma_f32_16x16x32_f16(a[m], b[f], acc[m][f], 0, 0, 0);
    }
    __syncthreads();   // drains vmcnt (stage) + lgkm, and fences buffer reuse
  }

  // Epilogue: interleaved re/im rows => sum of squares over the wave's 64
  // N-rows = sum over its 32 js of (re^2+im^2). Partial chunk index:
  // pp = blockIdx.y*2 + wn  (covers js pp*32 .. pp*32+31).
  const int pp = blockIdx.y * 2 + wn;
  #pragma unroll
  for (int m = 0; m < 4; ++m) {
    f32x4v p = f32x4v{0.f, 0.f, 0.f, 0.f};
    #pragma unroll
    for (int f = 0; f < 4; ++f) p += acc[m][f] * acc[m][f];
    #pragma unroll
    for (int msk = 1; msk < 16; msk <<= 1) {
      p.x += __shfl_xor(p.x, msk, 64);
      p.y += __shfl_xor(p.y, msk, 64);
      p.z += __shfl_xor(p.z, msk, 64);
      p.w += __shfl_xor(p.w, msk, 64);
    }
    if (lr == 0) {
      const int rbase = row0 + wm * 64 + m * 16 + (lane >> 4) * 4;
      float* dst = part + (size_t)pp * B + rbase;
      dst[0] = p.x; dst[1] = p.y; dst[2] = p.z; dst[3] = p.w;
    }
  }
}

// logits from 32 chunk partials: sign0 = bit9(j0) -> pp&16, sign1 = bit8 -> pp&8.
__global__ __launch_bounds__(1024) void nll_mean(const float* __restrict__ part,
                                                 const int* __restrict__ y,
                                                 float* __restrict__ out, int B) {
  const int t = threadIdx.x;
  const int rpt = B / 1024;
  float s = 0.f;
  for (int rr = 0; rr < rpt; ++rr) {
    const int row = t + rr * 1024;
    float q0 = 0.f, q1 = 0.f, nn = 0.f;
    #pragma unroll
    for (int pp = 0; pp < 32; ++pp) {
      const float P = part[(size_t)pp * B + row];
      q0 += (pp & 16) ? -P : P;
      q1 += (pp & 8) ? -P : P;
      nn += P;
    }
    const float z0 = q0 / nn, z1 = q1 / nn;
    const float mx = fmaxf(z0, z1);
    const float lse = mx + logf(expf(z0 - mx) + expf(z1 - mx));
    const float ly = (y[row] == 0) ? z0 : z1;
    s += lse - ly;
  }
  #pragma unroll
  for (int msk = 1; msk < 64; msk <<= 1) s += __shfl_xor(s, msk, 64);
  __shared__ float red[16];
  if ((t & 63) == 0) red[t >> 6] = s;
  __syncthreads();
  if (t == 0) {
    float tot = 0.f;
    #pragma unroll
    for (int q = 0; q < 16; ++q) tot += red[q];
    out[0] = tot / (float)B;
  }
}

} // namespace

extern "C" void kernel_launch(void* const* d_in, const int* in_sizes, int n_in,
                              void* d_out, int out_size, void* d_ws, size_t ws_size,
                              hipStream_t stream) {
  const float* x  = (const float*)d_in[0];
  const int*   y  = (const int*)d_in[1];
  const float* w  = (const float*)d_in[2];
  const float* w1 = (const float*)d_in[3];
  const float* w2 = (const float*)d_in[4];
  float* out = (float*)d_out;

  const int B = in_sizes[0] / 784;      // 8192

  char* ws = (char*)d_ws;
  float*    mats = (float*)ws;                                   // 6.7 KB
  _Float16* Wt   = (_Float16*)(ws + 8192);                       // 4 MB
  _Float16* Xh   = (_Float16*)(ws + 8192 + (size_t)2048 * 1024 * 2);   // 16 MB
  float*    part = (float*)(ws + 8192 + (size_t)2048 * 1024 * 2 + (size_t)B * 1024 * 2);

  make_mats<<<1, 128, 0, stream>>>(w, w1, w2, mats);
  build_W<<<256, 256, 0, stream>>>(mats, Wt);
  xconv<<<(B * 128) / 256, 256, 0, stream>>>(x, Xh);
  gemm_z<<<dim3(B / 128, 16), 256, 0, stream>>>(Xh, Wt, part, B);
  nll_mean<<<1, 1024, 0, stream>>>(part, y, out, B);
}

// Round 7
// 119.949 us; speedup vs baseline: 4.9877x; 1.1490x over previous
//
#include <hip/hip_runtime.h>

// CCQC classifier, GEMM formulation.
//   1. make_mats: fuse rotations into 105 2x2 gate matrices (packed form).
//   2. build_W:  REVERSED ADJOINT circuit on 1024 basis states -> rows of U.
//      R7: 4 waves per state (256-thread block, 4 f32x2 regs/lane);
//      j = (wv<<8)|(k<<6)|lane. Gates on bits 8-9 exchange via LDS.
//      16 waves/CU vs old 4 (occupancy was the build_W bottleneck).
//      Wt INTERLEAVED: row 2j = Re U[j][:], row 2j+1 = Im U[j][:].
//   3. xconv:    X fp32 (8192x784) -> fp16 padded (8192x1024).
//   4. gemm_z:   C = Xh * Wt^T, M=8192 N=2048 K=832, 128x128 tile, BK=64,
//      double-buffered global_load_lds staging, fused |psi|^2 epilogue
//      -> 32 sign-uniform chunk partials.
//   5. nll_mean: logits from chunk partials, log-softmax NLL, mean.

namespace {

typedef float f32x2 __attribute__((ext_vector_type(2)));
typedef _Float16 f16x8 __attribute__((ext_vector_type(8)));
typedef float f32x4v __attribute__((ext_vector_type(4)));

__device__ __forceinline__ f32x2 swap2(f32x2 v) {
  return __builtin_shufflevector(v, v, 1, 0);
}
__device__ __forceinline__ f32x2 shfl_xor2(f32x2 v, int lm) {
  f32x2 r;
  r.x = __shfl_xor(v.x, lm, 64);
  r.y = __shfl_xor(v.y, lm, 64);
  return r;
}
__device__ __forceinline__ f32x2 sel2(bool c, f32x2 a, f32x2 b) {
  f32x2 r; r.x = c ? a.x : b.x; r.y = c ? a.y : b.y; return r;
}

struct c2 { float r, i; };
struct m2c { c2 a00, a01, a10, a11; };

__device__ __forceinline__ c2 cmul(c2 x, c2 y) { return {x.r*y.r - x.i*y.i, x.r*y.i + x.i*y.r}; }
__device__ __forceinline__ c2 cadd(c2 x, c2 y) { return {x.r + y.r, x.i + y.i}; }
__device__ __forceinline__ m2c mmul(m2c A, m2c B) {
  m2c C;
  C.a00 = cadd(cmul(A.a00, B.a00), cmul(A.a01, B.a10));
  C.a01 = cadd(cmul(A.a00, B.a01), cmul(A.a01, B.a11));
  C.a10 = cadd(cmul(A.a10, B.a00), cmul(A.a11, B.a10));
  C.a11 = cadd(cmul(A.a10, B.a01), cmul(A.a11, B.a11));
  return C;
}
__device__ __forceinline__ m2c mrx(float t) {
  float c = cosf(0.5f * t), s = sinf(0.5f * t);
  return { {c, 0.f}, {0.f, -s}, {0.f, -s}, {c, 0.f} };
}
__device__ __forceinline__ m2c mrz(float t) {
  float c = cosf(0.5f * t), s = sinf(0.5f * t);
  return { {c, -s}, {0.f, 0.f}, {0.f, 0.f}, {c, s} };
}

// Per matrix 16 floats: for each entry e of {00,01,10,11}: {re, re, -im, im}.
__global__ void make_mats(const float* __restrict__ w, const float* __restrict__ w1,
                          const float* __restrict__ w2, float* __restrict__ mats) {
  int t = threadIdx.x;
  m2c U{}; int idx = -1;
  if (t < 50) {
    int d = t / 10, i = t % 10;
    const float* p = w + (d * 10 + i) * 5;
    U = mmul(mrx(p[2]), mmul(mrz(p[1]), mrx(p[0])));
    if (i == 0 && d > 0) {
      m2c U0 = mmul(mrz(w2[d - 1]), mrx(w1[d - 1]));
      U = mmul(U, U0);
    }
    idx = d * 21 + i;
  } else if (t < 100) {
    int s = t - 50; int d = s / 10, i = s % 10;
    const float* p = w + (d * 10 + i) * 5;
    U = mmul(mrx(p[4]), mrz(p[3]));
    idx = d * 21 + 10 + i;
  } else if (t < 105) {
    int d = t - 100;
    U = mmul(mrz(w2[d]), mrx(w1[d]));
    idx = d * 21 + 20;
  }
  if (idx >= 0) {
    float* o = mats + idx * 16;
    const c2 e[4] = {U.a00, U.a01, U.a10, U.a11};
    #pragma unroll
    for (int q = 0; q < 4; ++q) {
      o[q*4 + 0] = e[q].r; o[q*4 + 1] = e[q].r;
      o[q*4 + 2] = -e[q].i; o[q*4 + 3] = e[q].i;
    }
  }
}

struct MatP { f32x2 u00r, u00i, u01r, u01i, u10r, u10i, u11r, u11i; };

__device__ __forceinline__ MatP ldmat(const float* __restrict__ mats, int idx) {
  const float4* p = reinterpret_cast<const float4*>(mats + idx * 16);
  float4 a = p[0], b = p[1], c = p[2], d = p[3];
  MatP m;
  m.u00r = f32x2{a.x, a.y}; m.u00i = f32x2{a.z, a.w};
  m.u01r = f32x2{b.x, b.y}; m.u01i = f32x2{b.z, b.w};
  m.u10r = f32x2{c.x, c.y}; m.u10i = f32x2{c.z, c.w};
  m.u11r = f32x2{d.x, d.y}; m.u11i = f32x2{d.z, d.w};
  return m;
}
__device__ __forceinline__ MatP adjmat(const float* __restrict__ mats, int idx) {
  MatP m = ldmat(mats, idx);
  MatP r;
  r.u00r = m.u00r; r.u00i = -m.u00i;
  r.u01r = m.u10r; r.u01i = -m.u10i;
  r.u10r = m.u01r; r.u10i = -m.u01i;
  r.u11r = m.u11r; r.u11i = -m.u11i;
  return r;
}

__device__ __forceinline__ f32x2 cmad(f32x2 acc, f32x2 cr2, f32x2 ci2, f32x2 v) {
  return acc + cr2 * v + ci2 * swap2(v);
}
__device__ __forceinline__ f32x2 cmulp(f32x2 cr2, f32x2 ci2, f32x2 v) {
  return cr2 * v + ci2 * swap2(v);
}

// ---- 4-reg (4 waves/state) gate appliers. cm_reg: reg-bit ctrl mask (0=all). ----
__device__ __forceinline__ void g_xlane(f32x2 (&s)[4], const int lm,
                                        const f32x2 cAr, const f32x2 cAi,
                                        const f32x2 cBr, const f32x2 cBi,
                                        const int cm_reg) {
  #pragma unroll
  for (int k = 0; k < 4; ++k) {
    if (cm_reg && !(k & cm_reg)) continue;
    const f32x2 p = shfl_xor2(s[k], lm);
    s[k] = cmad(cmulp(cAr, cAi, s[k]), cBr, cBi, p);
  }
}
__device__ __forceinline__ void g_local(f32x2 (&s)[4], const int kb, const MatP m,
                                        const int cm_reg) {
  const int tm = 1 << kb;
  #pragma unroll
  for (int k0 = 0; k0 < 4; ++k0) {
    if (k0 & tm) continue;
    if (cm_reg && !(k0 & cm_reg)) continue;
    const int k1 = k0 | tm;
    const f32x2 a = s[k0], b = s[k1];
    s[k0] = cmad(cmulp(m.u00r, m.u00i, a), m.u01r, m.u01i, b);
    s[k1] = cmad(cmulp(m.u10r, m.u10i, a), m.u11r, m.u11i, b);
  }
}
__device__ __forceinline__ void g_xwave(f32x2 (&s)[4], f32x2* lx, const int wv,
                                        const int lane, const int tb,
                                        const f32x2 cAr, const f32x2 cAi,
                                        const f32x2 cBr, const f32x2 cBi,
                                        const int cm_reg) {
  #pragma unroll
  for (int k = 0; k < 4; ++k) lx[(wv * 4 + k) * 64 + lane] = s[k];
  __syncthreads();
  const int pw = wv ^ (1 << tb);
  #pragma unroll
  for (int k = 0; k < 4; ++k) {
    if (cm_reg && !(k & cm_reg)) continue;
    const f32x2 p = lx[(pw * 4 + k) * 64 + lane];
    s[k] = cmad(cmulp(cAr, cAi, s[k]), cBr, cBi, p);
  }
  __syncthreads();
}

// bt: target j-bit; bc: ctrl j-bit or -1. All compile-time after unrolling.
__device__ __forceinline__ void apply_gate(f32x2 (&s)[4], f32x2* lx, const int wv,
                                           const int lane, const MatP mIn,
                                           const int bt, const int bc) {
  MatP m = mIn;
  const f32x2 oner{1.f, 1.f}, zero{0.f, 0.f};
  int cm_reg = 0;
  bool fold = false, cl = true;
  if (bc >= 8)      { cl = ((wv >> (bc - 8)) & 1) != 0; fold = true; }
  else if (bc >= 6) { cm_reg = 1 << (bc - 6); }
  else if (bc >= 0) { cl = ((lane >> bc) & 1) != 0; fold = true; }

  if (bt >= 8) {
    const int tb = bt - 8;
    const bool hi = ((wv >> tb) & 1) != 0;
    f32x2 cAr = sel2(hi, m.u11r, m.u00r), cAi = sel2(hi, m.u11i, m.u00i);
    f32x2 cBr = sel2(hi, m.u10r, m.u01r), cBi = sel2(hi, m.u10i, m.u01i);
    if (fold) {
      cAr = sel2(cl, cAr, oner); cAi = sel2(cl, cAi, zero);
      cBr = sel2(cl, cBr, zero); cBi = sel2(cl, cBi, zero);
    }
    g_xwave(s, lx, wv, lane, tb, cAr, cAi, cBr, cBi, cm_reg);
  } else if (bt >= 6) {
    if (fold) {
      m.u00r = sel2(cl, m.u00r, oner); m.u00i = sel2(cl, m.u00i, zero);
      m.u01r = sel2(cl, m.u01r, zero); m.u01i = sel2(cl, m.u01i, zero);
      m.u10r = sel2(cl, m.u10r, zero); m.u10i = sel2(cl, m.u10i, zero);
      m.u11r = sel2(cl, m.u11r, oner); m.u11i = sel2(cl, m.u11i, zero);
    }
    g_local(s, bt - 6, m, cm_reg);
  } else {
    const bool hi = ((lane >> bt) & 1) != 0;
    f32x2 cAr = sel2(hi, m.u11r, m.u00r), cAi = sel2(hi, m.u11i, m.u00i);
    f32x2 cBr = sel2(hi, m.u10r, m.u01r), cBi = sel2(hi, m.u10i, m.u01i);
    if (fold) {
      cAr = sel2(cl, cAr, oner); cAi = sel2(cl, cAi, zero);
      cBr = sel2(cl, cBr, zero); cBi = sel2(cl, cBi, zero);
    }
    g_xlane(s, 1 << bt, cAr, cAi, cBr, cBi, cm_reg);
  }
}

// Row n of U via reversed-adjoint circuit on basis e_n. One 256-thread block
// (4 waves) per state; j = (wv<<8)|(k<<6)|lane.
// Interleaved out: Wt[2n][j] = Re U[n][j]; Wt[2n+1][j] = Im U[n][j].
__global__ __launch_bounds__(256) void build_W(const float* __restrict__ mats,
                                               _Float16* __restrict__ Wt) {
  __shared__ f32x2 lx[4 * 4 * 64];   // 8 KB exchange buffer
  const int lane = threadIdx.x & 63;
  const int wv = threadIdx.x >> 6;
  const int n = blockIdx.x;

  f32x2 s[4];
  #pragma unroll
  for (int k = 0; k < 4; ++k) {
    const int j = (wv << 8) | (k << 6) | lane;
    s[k].x = (j == n) ? 1.f : 0.f;
    s[k].y = 0.f;
  }

  #pragma unroll
  for (int dd = 0; dd < 5; ++dd) {
    const int d = 4 - dd;
    if (d == 4) apply_gate(s, lx, wv, lane, adjmat(mats, d * 21 + 20), 9, -1);
    const int r = (d & 1) ? 3 : 1;
    #pragma unroll
    for (int ii = 0; ii < 10; ++ii) {
      const int i = 9 - ii;
      const int c = (i + r) % 10;
      apply_gate(s, lx, wv, lane, adjmat(mats, d * 21 + 10 + i), 9 - i, 9 - c);
    }
    #pragma unroll
    for (int ii = 0; ii < 10; ++ii) {
      const int i = 9 - ii;
      apply_gate(s, lx, wv, lane, adjmat(mats, d * 21 + i), 9 - i, -1);
    }
  }

  // psi = U^dagger e_n => U[n][j] = (s.x, -s.y)
  #pragma unroll
  for (int k = 0; k < 4; ++k) {
    const int j = (wv << 8) | (k << 6) | lane;
    Wt[(size_t)(2 * n) * 1024 + j] = (_Float16)s[k].x;
    Wt[(size_t)(2 * n + 1) * 1024 + j] = (_Float16)(-s[k].y);
  }
}

// X fp32 (B x 784) -> fp16 (B x 1024), zero-padded.
__global__ __launch_bounds__(256) void xconv(const float* __restrict__ x,
                                             _Float16* __restrict__ Xh) {
  const int t = blockIdx.x * 256 + threadIdx.x;
  const int b = t >> 7;
  const int j = (t & 127) * 8;
  f16x8 o;
  if (j < 784) {
    const float4* p = reinterpret_cast<const float4*>(x + (size_t)b * 784 + j);
    const float4 v0 = p[0], v1 = p[1];
    o[0] = (_Float16)v0.x; o[1] = (_Float16)v0.y;
    o[2] = (_Float16)v0.z; o[3] = (_Float16)v0.w;
    o[4] = (_Float16)v1.x; o[5] = (_Float16)v1.y;
    o[6] = (_Float16)v1.z; o[7] = (_Float16)v1.w;
  } else {
    #pragma unroll
    for (int q = 0; q < 8; ++q) o[q] = (_Float16)0.f;
  }
  *reinterpret_cast<f16x8*>(Xh + (size_t)b * 1024 + j) = o;
}

// ---------------- LDS-staged GEMM ----------------
// Tile 128(M) x 128(N-rows, interleaved re/im = 64 js), BK=64, 13 K-steps
// (K=832 covers the 784 nonzero cols). 4 waves = 2(M) x 2(N), 64x64 each.
#define GZ_NSTEP 13

__device__ __forceinline__ void stage_tiles(const _Float16* __restrict__ gA,
                                            const _Float16* __restrict__ gB,
                                            _Float16* sA, _Float16* sB,
                                            int k0, int wv, int lane) {
  // per tile: 128 rows x 64 f16 = 16KB = 16 chunks of 1024B (8 rows each);
  // wave wv stages chunks [wv*4, wv*4+4) of both A and B.
  const int rIn = lane >> 3;             // row within chunk
  const int colh = (lane & 7) * 8;       // f16 col offset
  #pragma unroll
  for (int c = 0; c < 4; ++c) {
    const int chunk = wv * 4 + c;
    const size_t grow = (size_t)(chunk * 8 + rIn) * 1024 + k0 + colh;
    auto* la = (__attribute__((address_space(3))) void*)(sA + chunk * 512 + lane * 8);
    __builtin_amdgcn_global_load_lds(
        (const __attribute__((address_space(1))) void*)(gA + grow), la, 16, 0, 0);
    auto* lb = (__attribute__((address_space(3))) void*)(sB + chunk * 512 + lane * 8);
    __builtin_amdgcn_global_load_lds(
        (const __attribute__((address_space(1))) void*)(gB + grow), lb, 16, 0, 0);
  }
}

__global__ __launch_bounds__(256) void gemm_z(const _Float16* __restrict__ Xh,
                                              const _Float16* __restrict__ Wt,
                                              float* __restrict__ part, int B) {
  __shared__ _Float16 smA[2][128 * 64];
  __shared__ _Float16 smB[2][128 * 64];

  const int tid = threadIdx.x;
  const int lane = tid & 63;
  const int wv = tid >> 6;
  const int wm = wv >> 1, wn = wv & 1;
  const int row0 = blockIdx.x * 128;
  const int n0 = blockIdx.y * 128;

  const _Float16* gA = Xh + (size_t)row0 * 1024;
  const _Float16* gB = Wt + (size_t)n0 * 1024;

  const int lr = lane & 15;
  const int lk = (lane >> 4) * 8;

  f32x4v acc[4][4];
  #pragma unroll
  for (int m = 0; m < 4; ++m)
    #pragma unroll
    for (int f = 0; f < 4; ++f) acc[m][f] = f32x4v{0.f, 0.f, 0.f, 0.f};

  stage_tiles(gA, gB, smA[0], smB[0], 0, wv, lane);
  __syncthreads();

  for (int t = 0; t < GZ_NSTEP; ++t) {
    const int cur = t & 1;
    if (t + 1 < GZ_NSTEP)
      stage_tiles(gA, gB, smA[cur ^ 1], smB[cur ^ 1], (t + 1) * 64, wv, lane);

    #pragma unroll
    for (int kk = 0; kk < 2; ++kk) {
      f16x8 a[4], b[4];
      #pragma unroll
      for (int m = 0; m < 4; ++m)
        a[m] = *reinterpret_cast<const f16x8*>(
            &smA[cur][(wm * 64 + m * 16 + lr) * 64 + kk * 32 + lk]);
      #pragma unroll
      for (int f = 0; f < 4; ++f)
        b[f] = *reinterpret_cast<const f16x8*>(
            &smB[cur][(wn * 64 + f * 16 + lr) * 64 + kk * 32 + lk]);
      #pragma unroll
      for (int m = 0; m < 4; ++m)
        #pragma unroll
        for (int f = 0; f < 4; ++f)
          acc[m][f] = __builtin_amdgcn_mfma_f32_16x16x32_f16(a[m], b[f], acc[m][f], 0, 0, 0);
    }
    __syncthreads();   // drains vmcnt (stage) + lgkm, and fences buffer reuse
  }

  // Epilogue: interleaved re/im rows => sum of squares over the wave's 64
  // N-rows = sum over its 32 js of (re^2+im^2). Partial chunk index:
  // pp = blockIdx.y*2 + wn  (covers js pp*32 .. pp*32+31).
  const int pp = blockIdx.y * 2 + wn;
  #pragma unroll
  for (int m = 0; m < 4; ++m) {
    f32x4v p = f32x4v{0.f, 0.f, 0.f, 0.f};
    #pragma unroll
    for (int f = 0; f < 4; ++f) p += acc[m][f] * acc[m][f];
    #pragma unroll
    for (int msk = 1; msk < 16; msk <<= 1) {
      p.x += __shfl_xor(p.x, msk, 64);
      p.y += __shfl_xor(p.y, msk, 64);
      p.z += __shfl_xor(p.z, msk, 64);
      p.w += __shfl_xor(p.w, msk, 64);
    }
    if (lr == 0) {
      const int rbase = row0 + wm * 64 + m * 16 + (lane >> 4) * 4;
      float* dst = part + (size_t)pp * B + rbase;
      dst[0] = p.x; dst[1] = p.y; dst[2] = p.z; dst[3] = p.w;
    }
  }
}

// logits from 32 chunk partials: sign0 = bit9(j0) -> pp&16, sign1 = bit8 -> pp&8.
__global__ __launch_bounds__(1024) void nll_mean(const float* __restrict__ part,
                                                 const int* __restrict__ y,
                                                 float* __restrict__ out, int B) {
  const int t = threadIdx.x;
  const int rpt = B / 1024;
  float s = 0.f;
  for (int rr = 0; rr < rpt; ++rr) {
    const int row = t + rr * 1024;
    float q0 = 0.f, q1 = 0.f, nn = 0.f;
    #pragma unroll
    for (int pp = 0; pp < 32; ++pp) {
      const float P = part[(size_t)pp * B + row];
      q0 += (pp & 16) ? -P : P;
      q1 += (pp & 8) ? -P : P;
      nn += P;
    }
    const float z0 = q0 / nn, z1 = q1 / nn;
    const float mx = fmaxf(z0, z1);
    const float lse = mx + logf(expf(z0 - mx) + expf(z1 - mx));
    const float ly = (y[row] == 0) ? z0 : z1;
    s += lse - ly;
  }
  #pragma unroll
  for (int msk = 1; msk < 64; msk <<= 1) s += __shfl_xor(s, msk, 64);
  __shared__ float red[16];
  if ((t & 63) == 0) red[t >> 6] = s;
  __syncthreads();
  if (t == 0) {
    float tot = 0.f;
    #pragma unroll
    for (int q = 0; q < 16; ++q) tot += red[q];
    out[0] = tot / (float)B;
  }
}

} // namespace

extern "C" void kernel_launch(void* const* d_in, const int* in_sizes, int n_in,
                              void* d_out, int out_size, void* d_ws, size_t ws_size,
                              hipStream_t stream) {
  const float* x  = (const float*)d_in[0];
  const int*   y  = (const int*)d_in[1];
  const float* w  = (const float*)d_in[2];
  const float* w1 = (const float*)d_in[3];
  const float* w2 = (const float*)d_in[4];
  float* out = (float*)d_out;

  const int B = in_sizes[0] / 784;      // 8192

  char* ws = (char*)d_ws;
  float*    mats = (float*)ws;                                   // 6.7 KB
  _Float16* Wt   = (_Float16*)(ws + 8192);                       // 4 MB
  _Float16* Xh   = (_Float16*)(ws + 8192 + (size_t)2048 * 1024 * 2);   // 16 MB
  float*    part = (float*)(ws + 8192 + (size_t)2048 * 1024 * 2 + (size_t)B * 1024 * 2);

  make_mats<<<1, 128, 0, stream>>>(w, w1, w2, mats);
  build_W<<<1024, 256, 0, stream>>>(mats, Wt);
  xconv<<<(B * 128) / 256, 256, 0, stream>>>(x, Xh);
  gemm_z<<<dim3(B / 128, 16), 256, 0, stream>>>(Xh, Wt, part, B);
  nll_mean<<<1, 1024, 0, stream>>>(part, y, out, B);
}

// Round 8
// 106.254 us; speedup vs baseline: 5.6306x; 1.1289x over previous
//
#include <hip/hip_runtime.h>

// CCQC classifier, GEMM formulation.
//   1. make_mats: fuse rotations into 105 2x2 gate matrices (packed form).
//   2. build_W:  REVERSED ADJOINT circuit on 1024 basis states -> rows of U.
//      4 waves per state (256-thread block, 4 f32x2 regs/lane);
//      j = (wv<<8)|(k<<6)|lane. Gates on bits 8-9 exchange via LDS.
//      Wt INTERLEAVED: row 2j = Re U[j][:], row 2j+1 = Im U[j][:].
//   3. xconv:    X fp32 (8192x784) -> fp16 padded (8192x1024).
//   4. gemm_z:   C = Xh * Wt^T, M=8192 N=2048 K=832, 128x128 tile, BK=64,
//      double-buffered global_load_lds staging. R8: XOR bank-swizzle
//      (slot ^= row&7, on SOURCE addr + ds_read addr; LDS dest linear --
//      rule #21 both-sides) to kill the 16-way ds_read_b128 conflict.
//      Fused |psi|^2 epilogue -> 32 sign-uniform chunk partials.
//   5. nll_mean: logits from chunk partials, log-softmax NLL, mean.

namespace {

typedef float f32x2 __attribute__((ext_vector_type(2)));
typedef _Float16 f16x8 __attribute__((ext_vector_type(8)));
typedef float f32x4v __attribute__((ext_vector_type(4)));

__device__ __forceinline__ f32x2 swap2(f32x2 v) {
  return __builtin_shufflevector(v, v, 1, 0);
}
__device__ __forceinline__ f32x2 shfl_xor2(f32x2 v, int lm) {
  f32x2 r;
  r.x = __shfl_xor(v.x, lm, 64);
  r.y = __shfl_xor(v.y, lm, 64);
  return r;
}
__device__ __forceinline__ f32x2 sel2(bool c, f32x2 a, f32x2 b) {
  f32x2 r; r.x = c ? a.x : b.x; r.y = c ? a.y : b.y; return r;
}

struct c2 { float r, i; };
struct m2c { c2 a00, a01, a10, a11; };

__device__ __forceinline__ c2 cmul(c2 x, c2 y) { return {x.r*y.r - x.i*y.i, x.r*y.i + x.i*y.r}; }
__device__ __forceinline__ c2 cadd(c2 x, c2 y) { return {x.r + y.r, x.i + y.i}; }
__device__ __forceinline__ m2c mmul(m2c A, m2c B) {
  m2c C;
  C.a00 = cadd(cmul(A.a00, B.a00), cmul(A.a01, B.a10));
  C.a01 = cadd(cmul(A.a00, B.a01), cmul(A.a01, B.a11));
  C.a10 = cadd(cmul(A.a10, B.a00), cmul(A.a11, B.a10));
  C.a11 = cadd(cmul(A.a10, B.a01), cmul(A.a11, B.a11));
  return C;
}
__device__ __forceinline__ m2c mrx(float t) {
  float c = cosf(0.5f * t), s = sinf(0.5f * t);
  return { {c, 0.f}, {0.f, -s}, {0.f, -s}, {c, 0.f} };
}
__device__ __forceinline__ m2c mrz(float t) {
  float c = cosf(0.5f * t), s = sinf(0.5f * t);
  return { {c, -s}, {0.f, 0.f}, {0.f, 0.f}, {c, s} };
}

// Per matrix 16 floats: for each entry e of {00,01,10,11}: {re, re, -im, im}.
__global__ void make_mats(const float* __restrict__ w, const float* __restrict__ w1,
                          const float* __restrict__ w2, float* __restrict__ mats) {
  int t = threadIdx.x;
  m2c U{}; int idx = -1;
  if (t < 50) {
    int d = t / 10, i = t % 10;
    const float* p = w + (d * 10 + i) * 5;
    U = mmul(mrx(p[2]), mmul(mrz(p[1]), mrx(p[0])));
    if (i == 0 && d > 0) {
      m2c U0 = mmul(mrz(w2[d - 1]), mrx(w1[d - 1]));
      U = mmul(U, U0);
    }
    idx = d * 21 + i;
  } else if (t < 100) {
    int s = t - 50; int d = s / 10, i = s % 10;
    const float* p = w + (d * 10 + i) * 5;
    U = mmul(mrx(p[4]), mrz(p[3]));
    idx = d * 21 + 10 + i;
  } else if (t < 105) {
    int d = t - 100;
    U = mmul(mrz(w2[d]), mrx(w1[d]));
    idx = d * 21 + 20;
  }
  if (idx >= 0) {
    float* o = mats + idx * 16;
    const c2 e[4] = {U.a00, U.a01, U.a10, U.a11};
    #pragma unroll
    for (int q = 0; q < 4; ++q) {
      o[q*4 + 0] = e[q].r; o[q*4 + 1] = e[q].r;
      o[q*4 + 2] = -e[q].i; o[q*4 + 3] = e[q].i;
    }
  }
}

struct MatP { f32x2 u00r, u00i, u01r, u01i, u10r, u10i, u11r, u11i; };

__device__ __forceinline__ MatP ldmat(const float* __restrict__ mats, int idx) {
  const float4* p = reinterpret_cast<const float4*>(mats + idx * 16);
  float4 a = p[0], b = p[1], c = p[2], d = p[3];
  MatP m;
  m.u00r = f32x2{a.x, a.y}; m.u00i = f32x2{a.z, a.w};
  m.u01r = f32x2{b.x, b.y}; m.u01i = f32x2{b.z, b.w};
  m.u10r = f32x2{c.x, c.y}; m.u10i = f32x2{c.z, c.w};
  m.u11r = f32x2{d.x, d.y}; m.u11i = f32x2{d.z, d.w};
  return m;
}
__device__ __forceinline__ MatP adjmat(const float* __restrict__ mats, int idx) {
  MatP m = ldmat(mats, idx);
  MatP r;
  r.u00r = m.u00r; r.u00i = -m.u00i;
  r.u01r = m.u10r; r.u01i = -m.u10i;
  r.u10r = m.u01r; r.u10i = -m.u01i;
  r.u11r = m.u11r; r.u11i = -m.u11i;
  return r;
}

__device__ __forceinline__ f32x2 cmad(f32x2 acc, f32x2 cr2, f32x2 ci2, f32x2 v) {
  return acc + cr2 * v + ci2 * swap2(v);
}
__device__ __forceinline__ f32x2 cmulp(f32x2 cr2, f32x2 ci2, f32x2 v) {
  return cr2 * v + ci2 * swap2(v);
}

// ---- 4-reg (4 waves/state) gate appliers. cm_reg: reg-bit ctrl mask (0=all). ----
__device__ __forceinline__ void g_xlane(f32x2 (&s)[4], const int lm,
                                        const f32x2 cAr, const f32x2 cAi,
                                        const f32x2 cBr, const f32x2 cBi,
                                        const int cm_reg) {
  #pragma unroll
  for (int k = 0; k < 4; ++k) {
    if (cm_reg && !(k & cm_reg)) continue;
    const f32x2 p = shfl_xor2(s[k], lm);
    s[k] = cmad(cmulp(cAr, cAi, s[k]), cBr, cBi, p);
  }
}
__device__ __forceinline__ void g_local(f32x2 (&s)[4], const int kb, const MatP m,
                                        const int cm_reg) {
  const int tm = 1 << kb;
  #pragma unroll
  for (int k0 = 0; k0 < 4; ++k0) {
    if (k0 & tm) continue;
    if (cm_reg && !(k0 & cm_reg)) continue;
    const int k1 = k0 | tm;
    const f32x2 a = s[k0], b = s[k1];
    s[k0] = cmad(cmulp(m.u00r, m.u00i, a), m.u01r, m.u01i, b);
    s[k1] = cmad(cmulp(m.u10r, m.u10i, a), m.u11r, m.u11i, b);
  }
}
__device__ __forceinline__ void g_xwave(f32x2 (&s)[4], f32x2* lx, const int wv,
                                        const int lane, const int tb,
                                        const f32x2 cAr, const f32x2 cAi,
                                        const f32x2 cBr, const f32x2 cBi,
                                        const int cm_reg) {
  #pragma unroll
  for (int k = 0; k < 4; ++k) lx[(wv * 4 + k) * 64 + lane] = s[k];
  __syncthreads();
  const int pw = wv ^ (1 << tb);
  #pragma unroll
  for (int k = 0; k < 4; ++k) {
    if (cm_reg && !(k & cm_reg)) continue;
    const f32x2 p = lx[(pw * 4 + k) * 64 + lane];
    s[k] = cmad(cmulp(cAr, cAi, s[k]), cBr, cBi, p);
  }
  __syncthreads();
}

// bt: target j-bit; bc: ctrl j-bit or -1. All compile-time after unrolling.
__device__ __forceinline__ void apply_gate(f32x2 (&s)[4], f32x2* lx, const int wv,
                                           const int lane, const MatP mIn,
                                           const int bt, const int bc) {
  MatP m = mIn;
  const f32x2 oner{1.f, 1.f}, zero{0.f, 0.f};
  int cm_reg = 0;
  bool fold = false, cl = true;
  if (bc >= 8)      { cl = ((wv >> (bc - 8)) & 1) != 0; fold = true; }
  else if (bc >= 6) { cm_reg = 1 << (bc - 6); }
  else if (bc >= 0) { cl = ((lane >> bc) & 1) != 0; fold = true; }

  if (bt >= 8) {
    const int tb = bt - 8;
    const bool hi = ((wv >> tb) & 1) != 0;
    f32x2 cAr = sel2(hi, m.u11r, m.u00r), cAi = sel2(hi, m.u11i, m.u00i);
    f32x2 cBr = sel2(hi, m.u10r, m.u01r), cBi = sel2(hi, m.u10i, m.u01i);
    if (fold) {
      cAr = sel2(cl, cAr, oner); cAi = sel2(cl, cAi, zero);
      cBr = sel2(cl, cBr, zero); cBi = sel2(cl, cBi, zero);
    }
    g_xwave(s, lx, wv, lane, tb, cAr, cAi, cBr, cBi, cm_reg);
  } else if (bt >= 6) {
    if (fold) {
      m.u00r = sel2(cl, m.u00r, oner); m.u00i = sel2(cl, m.u00i, zero);
      m.u01r = sel2(cl, m.u01r, zero); m.u01i = sel2(cl, m.u01i, zero);
      m.u10r = sel2(cl, m.u10r, zero); m.u10i = sel2(cl, m.u10i, zero);
      m.u11r = sel2(cl, m.u11r, oner); m.u11i = sel2(cl, m.u11i, zero);
    }
    g_local(s, bt - 6, m, cm_reg);
  } else {
    const bool hi = ((lane >> bt) & 1) != 0;
    f32x2 cAr = sel2(hi, m.u11r, m.u00r), cAi = sel2(hi, m.u11i, m.u00i);
    f32x2 cBr = sel2(hi, m.u10r, m.u01r), cBi = sel2(hi, m.u10i, m.u01i);
    if (fold) {
      cAr = sel2(cl, cAr, oner); cAi = sel2(cl, cAi, zero);
      cBr = sel2(cl, cBr, zero); cBi = sel2(cl, cBi, zero);
    }
    g_xlane(s, 1 << bt, cAr, cAi, cBr, cBi, cm_reg);
  }
}

// Row n of U via reversed-adjoint circuit on basis e_n. One 256-thread block
// (4 waves) per state; j = (wv<<8)|(k<<6)|lane.
// Interleaved out: Wt[2n][j] = Re U[n][j]; Wt[2n+1][j] = Im U[n][j].
__global__ __launch_bounds__(256) void build_W(const float* __restrict__ mats,
                                               _Float16* __restrict__ Wt) {
  __shared__ f32x2 lx[4 * 4 * 64];   // 8 KB exchange buffer
  const int lane = threadIdx.x & 63;
  const int wv = threadIdx.x >> 6;
  const int n = blockIdx.x;

  f32x2 s[4];
  #pragma unroll
  for (int k = 0; k < 4; ++k) {
    const int j = (wv << 8) | (k << 6) | lane;
    s[k].x = (j == n) ? 1.f : 0.f;
    s[k].y = 0.f;
  }

  #pragma unroll
  for (int dd = 0; dd < 5; ++dd) {
    const int d = 4 - dd;
    if (d == 4) apply_gate(s, lx, wv, lane, adjmat(mats, d * 21 + 20), 9, -1);
    const int r = (d & 1) ? 3 : 1;
    #pragma unroll
    for (int ii = 0; ii < 10; ++ii) {
      const int i = 9 - ii;
      const int c = (i + r) % 10;
      apply_gate(s, lx, wv, lane, adjmat(mats, d * 21 + 10 + i), 9 - i, 9 - c);
    }
    #pragma unroll
    for (int ii = 0; ii < 10; ++ii) {
      const int i = 9 - ii;
      apply_gate(s, lx, wv, lane, adjmat(mats, d * 21 + i), 9 - i, -1);
    }
  }

  // psi = U^dagger e_n => U[n][j] = (s.x, -s.y)
  #pragma unroll
  for (int k = 0; k < 4; ++k) {
    const int j = (wv << 8) | (k << 6) | lane;
    Wt[(size_t)(2 * n) * 1024 + j] = (_Float16)s[k].x;
    Wt[(size_t)(2 * n + 1) * 1024 + j] = (_Float16)(-s[k].y);
  }
}

// X fp32 (B x 784) -> fp16 (B x 1024), zero-padded.
__global__ __launch_bounds__(256) void xconv(const float* __restrict__ x,
                                             _Float16* __restrict__ Xh) {
  const int t = blockIdx.x * 256 + threadIdx.x;
  const int b = t >> 7;
  const int j = (t & 127) * 8;
  f16x8 o;
  if (j < 784) {
    const float4* p = reinterpret_cast<const float4*>(x + (size_t)b * 784 + j);
    const float4 v0 = p[0], v1 = p[1];
    o[0] = (_Float16)v0.x; o[1] = (_Float16)v0.y;
    o[2] = (_Float16)v0.z; o[3] = (_Float16)v0.w;
    o[4] = (_Float16)v1.x; o[5] = (_Float16)v1.y;
    o[6] = (_Float16)v1.z; o[7] = (_Float16)v1.w;
  } else {
    #pragma unroll
    for (int q = 0; q < 8; ++q) o[q] = (_Float16)0.f;
  }
  *reinterpret_cast<f16x8*>(Xh + (size_t)b * 1024 + j) = o;
}

// ---------------- LDS-staged GEMM ----------------
// Tile 128(M) x 128(N-rows, interleaved re/im = 64 js), BK=64, 13 K-steps
// (K=832 covers the 784 nonzero cols). 4 waves = 2(M) x 2(N), 64x64 each.
// LDS swizzle: row r of a tile holds its 8 16B-slots permuted s -> s^(r&7).
// Staged with linear LDS dest + swizzled GLOBAL source; read with same XOR.
#define GZ_NSTEP 13

__device__ __forceinline__ void stage_tiles(const _Float16* __restrict__ gA,
                                            const _Float16* __restrict__ gB,
                                            _Float16* sA, _Float16* sB,
                                            int k0, int wv, int lane) {
  // per tile: 128 rows x 64 f16 = 16KB = 16 chunks of 1024B (8 rows each);
  // wave wv stages chunks [wv*4, wv*4+4) of both A and B.
  const int rIn = lane >> 3;                    // row within chunk (0..7)
  const int colh = ((lane & 7) ^ rIn) * 8;      // swizzled source 16B-slot
  #pragma unroll
  for (int c = 0; c < 4; ++c) {
    const int chunk = wv * 4 + c;
    const size_t grow = (size_t)(chunk * 8 + rIn) * 1024 + k0 + colh;
    auto* la = (__attribute__((address_space(3))) void*)(sA + chunk * 512 + lane * 8);
    __builtin_amdgcn_global_load_lds(
        (const __attribute__((address_space(1))) void*)(gA + grow), la, 16, 0, 0);
    auto* lb = (__attribute__((address_space(3))) void*)(sB + chunk * 512 + lane * 8);
    __builtin_amdgcn_global_load_lds(
        (const __attribute__((address_space(1))) void*)(gB + grow), lb, 16, 0, 0);
  }
}

// LDS f16 offset for (row, 16B-slot) with the tile swizzle applied.
__device__ __forceinline__ int lds_off(int row, int slot) {
  return row * 64 + ((slot ^ (row & 7)) * 8);
}

__global__ __launch_bounds__(256) void gemm_z(const _Float16* __restrict__ Xh,
                                              const _Float16* __restrict__ Wt,
                                              float* __restrict__ part, int B) {
  __shared__ _Float16 smA[2][128 * 64];
  __shared__ _Float16 smB[2][128 * 64];

  const int tid = threadIdx.x;
  const int lane = tid & 63;
  const int wv = tid >> 6;
  const int wm = wv >> 1, wn = wv & 1;
  const int row0 = blockIdx.x * 128;
  const int n0 = blockIdx.y * 128;

  const _Float16* gA = Xh + (size_t)row0 * 1024;
  const _Float16* gB = Wt + (size_t)n0 * 1024;

  const int lr = lane & 15;
  const int lq = lane >> 4;       // 0..3: which 8-f16 K-slot within 32

  f32x4v acc[4][4];
  #pragma unroll
  for (int m = 0; m < 4; ++m)
    #pragma unroll
    for (int f = 0; f < 4; ++f) acc[m][f] = f32x4v{0.f, 0.f, 0.f, 0.f};

  stage_tiles(gA, gB, smA[0], smB[0], 0, wv, lane);
  __syncthreads();

  for (int t = 0; t < GZ_NSTEP; ++t) {
    const int cur = t & 1;
    if (t + 1 < GZ_NSTEP)
      stage_tiles(gA, gB, smA[cur ^ 1], smB[cur ^ 1], (t + 1) * 64, wv, lane);

    #pragma unroll
    for (int kk = 0; kk < 2; ++kk) {
      const int slot = kk * 4 + lq;
      f16x8 a[4], b[4];
      #pragma unroll
      for (int m = 0; m < 4; ++m) {
        const int row = wm * 64 + m * 16 + lr;
        a[m] = *reinterpret_cast<const f16x8*>(&smA[cur][lds_off(row, slot)]);
      }
      #pragma unroll
      for (int f = 0; f < 4; ++f) {
        const int row = wn * 64 + f * 16 + lr;
        b[f] = *reinterpret_cast<const f16x8*>(&smB[cur][lds_off(row, slot)]);
      }
      #pragma unroll
      for (int m = 0; m < 4; ++m)
        #pragma unroll
        for (int f = 0; f < 4; ++f)
          acc[m][f] = __builtin_amdgcn_mfma_f32_16x16x32_f16(a[m], b[f], acc[m][f], 0, 0, 0);
    }
    __syncthreads();   // drains vmcnt (stage) + lgkm, and fences buffer reuse
  }

  // Epilogue: interleaved re/im rows => sum of squares over the wave's 64
  // N-rows = sum over its 32 js of (re^2+im^2). Partial chunk index:
  // pp = blockIdx.y*2 + wn  (covers js pp*32 .. pp*32+31).
  const int pp = blockIdx.y * 2 + wn;
  #pragma unroll
  for (int m = 0; m < 4; ++m) {
    f32x4v p = f32x4v{0.f, 0.f, 0.f, 0.f};
    #pragma unroll
    for (int f = 0; f < 4; ++f) p += acc[m][f] * acc[m][f];
    #pragma unroll
    for (int msk = 1; msk < 16; msk <<= 1) {
      p.x += __shfl_xor(p.x, msk, 64);
      p.y += __shfl_xor(p.y, msk, 64);
      p.z += __shfl_xor(p.z, msk, 64);
      p.w += __shfl_xor(p.w, msk, 64);
    }
    if (lr == 0) {
      const int rbase = row0 + wm * 64 + m * 16 + lq * 4;
      float* dst = part + (size_t)pp * B + rbase;
      dst[0] = p.x; dst[1] = p.y; dst[2] = p.z; dst[3] = p.w;
    }
  }
}

// logits from 32 chunk partials: sign0 = bit9(j0) -> pp&16, sign1 = bit8 -> pp&8.
__global__ __launch_bounds__(1024) void nll_mean(const float* __restrict__ part,
                                                 const int* __restrict__ y,
                                                 float* __restrict__ out, int B) {
  const int t = threadIdx.x;
  const int rpt = B / 1024;
  float s = 0.f;
  for (int rr = 0; rr < rpt; ++rr) {
    const int row = t + rr * 1024;
    float q0 = 0.f, q1 = 0.f, nn = 0.f;
    #pragma unroll
    for (int pp = 0; pp < 32; ++pp) {
      const float P = part[(size_t)pp * B + row];
      q0 += (pp & 16) ? -P : P;
      q1 += (pp & 8) ? -P : P;
      nn += P;
    }
    const float z0 = q0 / nn, z1 = q1 / nn;
    const float mx = fmaxf(z0, z1);
    const float lse = mx + logf(expf(z0 - mx) + expf(z1 - mx));
    const float ly = (y[row] == 0) ? z0 : z1;
    s += lse - ly;
  }
  #pragma unroll
  for (int msk = 1; msk < 64; msk <<= 1) s += __shfl_xor(s, msk, 64);
  __shared__ float red[16];
  if ((t & 63) == 0) red[t >> 6] = s;
  __syncthreads();
  if (t == 0) {
    float tot = 0.f;
    #pragma unroll
    for (int q = 0; q < 16; ++q) tot += red[q];
    out[0] = tot / (float)B;
  }
}

} // namespace

extern "C" void kernel_launch(void* const* d_in, const int* in_sizes, int n_in,
                              void* d_out, int out_size, void* d_ws, size_t ws_size,
                              hipStream_t stream) {
  const float* x  = (const float*)d_in[0];
  const int*   y  = (const int*)d_in[1];
  const float* w  = (const float*)d_in[2];
  const float* w1 = (const float*)d_in[3];
  const float* w2 = (const float*)d_in[4];
  float* out = (float*)d_out;

  const int B = in_sizes[0] / 784;      // 8192

  char* ws = (char*)d_ws;
  float*    mats = (float*)ws;                                   // 6.7 KB
  _Float16* Wt   = (_Float16*)(ws + 8192);                       // 4 MB
  _Float16* Xh   = (_Float16*)(ws + 8192 + (size_t)2048 * 1024 * 2);   // 16 MB
  float*    part = (float*)(ws + 8192 + (size_t)2048 * 1024 * 2 + (size_t)B * 1024 * 2);

  make_mats<<<1, 128, 0, stream>>>(w, w1, w2, mats);
  build_W<<<1024, 256, 0, stream>>>(mats, Wt);
  xconv<<<(B * 128) / 256, 256, 0, stream>>>(x, Xh);
  gemm_z<<<dim3(B / 128, 16), 256, 0, stream>>>(Xh, Wt, part, B);
  nll_mean<<<1, 1024, 0, stream>>>(part, y, out, B);
}

// Round 9
// 98.595 us; speedup vs baseline: 6.0680x; 1.0777x over previous
//
#include <hip/hip_runtime.h>

// CCQC classifier, GEMM formulation. R9: fused prep kernel.
//   1. qprep (blocks 0..1023): build rows of U via REVERSED ADJOINT circuit.
//      Each block computes the 101-gate pre-adjointed program into LDS
//      (no global matrix loads in the gate chain, no separate make_mats),
//      then 4 waves x 4 f32x2 regs simulate basis state n = blockIdx.
//      Cross-wave gates (j-bits 8,9) use a DOUBLE-BUFFERED LDS exchange
//      (1 barrier per exchange). Wt interleaved: row 2j=Re, 2j+1=Im.
//      qprep (blocks 1024..5119): xconv X fp32 (8192x784) -> fp16 (8192x1024)
//      -- independent memory-bound work overlapping build_W's latency stalls.
//   2. gemm_z: C = Xh * Wt^T, M=8192 N=2048 K=832, 128x128 tile, BK=64,
//      double-buffered global_load_lds, XOR bank-swizzle (both-sides),
//      fused |psi|^2 epilogue -> 32 sign-uniform chunk partials.
//   3. nll_mean: logits from chunk partials, log-softmax NLL, mean.

namespace {

typedef float f32x2 __attribute__((ext_vector_type(2)));
typedef _Float16 f16x8 __attribute__((ext_vector_type(8)));
typedef float f32x4v __attribute__((ext_vector_type(4)));

__device__ __forceinline__ f32x2 swap2(f32x2 v) {
  return __builtin_shufflevector(v, v, 1, 0);
}
__device__ __forceinline__ f32x2 shfl_xor2(f32x2 v, int lm) {
  f32x2 r;
  r.x = __shfl_xor(v.x, lm, 64);
  r.y = __shfl_xor(v.y, lm, 64);
  return r;
}
__device__ __forceinline__ f32x2 sel2(bool c, f32x2 a, f32x2 b) {
  f32x2 r; r.x = c ? a.x : b.x; r.y = c ? a.y : b.y; return r;
}

struct c2 { float r, i; };
struct m2c { c2 a00, a01, a10, a11; };

__device__ __forceinline__ c2 cmul(c2 x, c2 y) { return {x.r*y.r - x.i*y.i, x.r*y.i + x.i*y.r}; }
__device__ __forceinline__ c2 cadd(c2 x, c2 y) { return {x.r + y.r, x.i + y.i}; }
__device__ __forceinline__ c2 conjc(c2 a) { return {a.r, -a.i}; }
__device__ __forceinline__ m2c mmul(m2c A, m2c B) {
  m2c C;
  C.a00 = cadd(cmul(A.a00, B.a00), cmul(A.a01, B.a10));
  C.a01 = cadd(cmul(A.a00, B.a01), cmul(A.a01, B.a11));
  C.a10 = cadd(cmul(A.a10, B.a00), cmul(A.a11, B.a10));
  C.a11 = cadd(cmul(A.a10, B.a01), cmul(A.a11, B.a11));
  return C;
}
__device__ __forceinline__ m2c mrx(float t) {
  float c = cosf(0.5f * t), s = sinf(0.5f * t);
  return { {c, 0.f}, {0.f, -s}, {0.f, -s}, {c, 0.f} };
}
__device__ __forceinline__ m2c mrz(float t) {
  float c = cosf(0.5f * t), s = sinf(0.5f * t);
  return { {c, -s}, {0.f, 0.f}, {0.f, 0.f}, {c, s} };
}

struct MatP { f32x2 u00r, u00i, u01r, u01i, u10r, u10i, u11r, u11i; };

// Load packed matrix from the LDS program.
__device__ __forceinline__ MatP ldmatL(const float* progL, int slot) {
  const float4* p = reinterpret_cast<const float4*>(progL + slot * 16);
  float4 a = p[0], b = p[1], c = p[2], d = p[3];
  MatP m;
  m.u00r = f32x2{a.x, a.y}; m.u00i = f32x2{a.z, a.w};
  m.u01r = f32x2{b.x, b.y}; m.u01i = f32x2{b.z, b.w};
  m.u10r = f32x2{c.x, c.y}; m.u10i = f32x2{c.z, c.w};
  m.u11r = f32x2{d.x, d.y}; m.u11i = f32x2{d.z, d.w};
  return m;
}

__device__ __forceinline__ f32x2 cmad(f32x2 acc, f32x2 cr2, f32x2 ci2, f32x2 v) {
  return acc + cr2 * v + ci2 * swap2(v);
}
__device__ __forceinline__ f32x2 cmulp(f32x2 cr2, f32x2 ci2, f32x2 v) {
  return cr2 * v + ci2 * swap2(v);
}

// ---- 4-reg (4 waves/state) gate appliers ----
__device__ __forceinline__ void g_xlane(f32x2 (&s)[4], const int lm,
                                        const f32x2 cAr, const f32x2 cAi,
                                        const f32x2 cBr, const f32x2 cBi,
                                        const int cm_reg) {
  #pragma unroll
  for (int k = 0; k < 4; ++k) {
    if (cm_reg && !(k & cm_reg)) continue;
    const f32x2 p = shfl_xor2(s[k], lm);
    s[k] = cmad(cmulp(cAr, cAi, s[k]), cBr, cBi, p);
  }
}
__device__ __forceinline__ void g_local(f32x2 (&s)[4], const int kb, const MatP m,
                                        const int cm_reg) {
  const int tm = 1 << kb;
  #pragma unroll
  for (int k0 = 0; k0 < 4; ++k0) {
    if (k0 & tm) continue;
    if (cm_reg && !(k0 & cm_reg)) continue;
    const int k1 = k0 | tm;
    const f32x2 a = s[k0], b = s[k1];
    s[k0] = cmad(cmulp(m.u00r, m.u00i, a), m.u01r, m.u01i, b);
    s[k1] = cmad(cmulp(m.u10r, m.u10i, a), m.u11r, m.u11i, b);
  }
}
// Single barrier per exchange: caller alternates lxb between two buffers.
__device__ __forceinline__ void g_xwave(f32x2 (&s)[4], f32x2* lxb, const int wv,
                                        const int lane, const int tb,
                                        const f32x2 cAr, const f32x2 cAi,
                                        const f32x2 cBr, const f32x2 cBi,
                                        const int cm_reg) {
  #pragma unroll
  for (int k = 0; k < 4; ++k) lxb[(wv * 4 + k) * 64 + lane] = s[k];
  __syncthreads();
  const int pw = wv ^ (1 << tb);
  #pragma unroll
  for (int k = 0; k < 4; ++k) {
    if (cm_reg && !(k & cm_reg)) continue;
    const f32x2 p = lxb[(pw * 4 + k) * 64 + lane];
    s[k] = cmad(cmulp(cAr, cAi, s[k]), cBr, cBi, p);
  }
}

__device__ __forceinline__ void apply_gate(f32x2 (&s)[4], f32x2* lxb, const int wv,
                                           const int lane, const MatP mIn,
                                           const int bt, const int bc) {
  MatP m = mIn;
  const f32x2 oner{1.f, 1.f}, zero{0.f, 0.f};
  int cm_reg = 0;
  bool fold = false, cl = true;
  if (bc >= 8)      { cl = ((wv >> (bc - 8)) & 1) != 0; fold = true; }
  else if (bc >= 6) { cm_reg = 1 << (bc - 6); }
  else if (bc >= 0) { cl = ((lane >> bc) & 1) != 0; fold = true; }

  if (bt >= 8) {
    const int tb = bt - 8;
    const bool hi = ((wv >> tb) & 1) != 0;
    f32x2 cAr = sel2(hi, m.u11r, m.u00r), cAi = sel2(hi, m.u11i, m.u00i);
    f32x2 cBr = sel2(hi, m.u10r, m.u01r), cBi = sel2(hi, m.u10i, m.u01i);
    if (fold) {
      cAr = sel2(cl, cAr, oner); cAi = sel2(cl, cAi, zero);
      cBr = sel2(cl, cBr, zero); cBi = sel2(cl, cBi, zero);
    }
    g_xwave(s, lxb, wv, lane, tb, cAr, cAi, cBr, cBi, cm_reg);
  } else if (bt >= 6) {
    if (fold) {
      m.u00r = sel2(cl, m.u00r, oner); m.u00i = sel2(cl, m.u00i, zero);
      m.u01r = sel2(cl, m.u01r, zero); m.u01i = sel2(cl, m.u01i, zero);
      m.u10r = sel2(cl, m.u10r, zero); m.u10i = sel2(cl, m.u10i, zero);
      m.u11r = sel2(cl, m.u11r, oner); m.u11i = sel2(cl, m.u11i, zero);
    }
    g_local(s, bt - 6, m, cm_reg);
  } else {
    const bool hi = ((lane >> bt) & 1) != 0;
    f32x2 cAr = sel2(hi, m.u11r, m.u00r), cAi = sel2(hi, m.u11i, m.u00i);
    f32x2 cBr = sel2(hi, m.u10r, m.u01r), cBi = sel2(hi, m.u10i, m.u01i);
    if (fold) {
      cAr = sel2(cl, cAr, oner); cAi = sel2(cl, cAi, zero);
      cBr = sel2(cl, cBr, zero); cBi = sel2(cl, cBi, zero);
    }
    g_xlane(s, 1 << bt, cAr, cAi, cBr, cBi, cm_reg);
  }
}

// Fused prep kernel. Blocks <1024: build row n=blockIdx of U.
// Blocks >=1024: xconv (independent, overlaps build latency).
// Program slot layout (execution order of the reversed-adjoint circuit):
//   layer dd=0 (d=4): slot0 = U0; 1..10 = CU i=9..0; 11..20 = U1 i=9..0.
//   layer dd>=1 (d=4-dd): base=21+(dd-1)*20: 0..9 = CU i=9..0; 10..19 = U1.
// U0[d<4] is pre-fused into U1[d+1, i=0] (no slot). 101 slots total.
__global__ __launch_bounds__(256) void qprep(const float* __restrict__ w,
                                             const float* __restrict__ w1,
                                             const float* __restrict__ w2,
                                             const float* __restrict__ x,
                                             _Float16* __restrict__ Wt,
                                             _Float16* __restrict__ Xh) {
  const int tid = threadIdx.x;
  if (blockIdx.x >= 1024) {
    // ---- xconv ----
    const int t = (blockIdx.x - 1024) * 256 + tid;
    const int b = t >> 7;
    const int j = (t & 127) * 8;
    f16x8 o;
    if (j < 784) {
      const float4* p = reinterpret_cast<const float4*>(x + (size_t)b * 784 + j);
      const float4 v0 = p[0], v1 = p[1];
      o[0] = (_Float16)v0.x; o[1] = (_Float16)v0.y;
      o[2] = (_Float16)v0.z; o[3] = (_Float16)v0.w;
      o[4] = (_Float16)v1.x; o[5] = (_Float16)v1.y;
      o[6] = (_Float16)v1.z; o[7] = (_Float16)v1.w;
    } else {
      #pragma unroll
      for (int q = 0; q < 8; ++q) o[q] = (_Float16)0.f;
    }
    *reinterpret_cast<f16x8*>(Xh + (size_t)b * 1024 + j) = o;
    return;
  }

  // ---- build_W ----
  __shared__ float progL[101 * 16];
  __shared__ f32x2 lx[2][1024];   // double-buffered exchange (8 KB each)

  if (tid < 105) {
    const int t = tid;
    m2c U{}; int slot = -1;
    if (t < 50) {
      const int d = t / 10, i = t % 10;
      const float* p = w + (d * 10 + i) * 5;
      U = mmul(mrx(p[2]), mmul(mrz(p[1]), mrx(p[0])));
      if (i == 0 && d > 0) {
        m2c U0 = mmul(mrz(w2[d - 1]), mrx(w1[d - 1]));
        U = mmul(U, U0);
      }
      const int dd = 4 - d;
      const int base = (dd == 0) ? 0 : 21 + (dd - 1) * 20;
      slot = base + ((d == 4) ? 11 : 10) + (9 - i);
    } else if (t < 100) {
      const int s = t - 50; const int d = s / 10, i = s % 10;
      const float* p = w + (d * 10 + i) * 5;
      U = mmul(mrx(p[4]), mrz(p[3]));
      const int dd = 4 - d;
      const int base = (dd == 0) ? 0 : 21 + (dd - 1) * 20;
      slot = base + ((d == 4) ? 1 : 0) + (9 - i);
    } else {
      const int d = t - 100;
      if (d == 4) {
        U = mmul(mrz(w2[d]), mrx(w1[d]));
        slot = 0;
      }
    }
    if (slot >= 0) {
      // Adjoint: A = U^dagger (conj-transpose), packed {a.r, a.r, -a.i, a.i}.
      const c2 A[4] = {conjc(U.a00), conjc(U.a10), conjc(U.a01), conjc(U.a11)};
      float* o = progL + slot * 16;
      #pragma unroll
      for (int q = 0; q < 4; ++q) {
        o[q*4 + 0] = A[q].r; o[q*4 + 1] = A[q].r;
        o[q*4 + 2] = -A[q].i; o[q*4 + 3] = A[q].i;
      }
    }
  }
  __syncthreads();

  const int lane = tid & 63;
  const int wv = tid >> 6;
  const int n = blockIdx.x;

  f32x2 s[4];
  #pragma unroll
  for (int k = 0; k < 4; ++k) {
    const int j = (wv << 8) | (k << 6) | lane;
    s[k].x = (j == n) ? 1.f : 0.f;
    s[k].y = 0.f;
  }

  int p = 0, ph = 0;
  #pragma unroll
  for (int dd = 0; dd < 5; ++dd) {
    const int d = 4 - dd;
    if (d == 4) {
      apply_gate(s, &lx[ph & 1][0], wv, lane, ldmatL(progL, p), 9, -1);
      ++p; ++ph;
    }
    const int r = (d & 1) ? 3 : 1;
    #pragma unroll
    for (int ii = 0; ii < 10; ++ii) {
      const int i = 9 - ii;
      const int c = (i + r) % 10;
      const int bt = 9 - i, bc = 9 - c;
      apply_gate(s, &lx[ph & 1][0], wv, lane, ldmatL(progL, p), bt, bc);
      ++p; if (bt >= 8) ++ph;
    }
    #pragma unroll
    for (int ii = 0; ii < 10; ++ii) {
      const int i = 9 - ii;
      const int bt = 9 - i;
      apply_gate(s, &lx[ph & 1][0], wv, lane, ldmatL(progL, p), bt, -1);
      ++p; if (bt >= 8) ++ph;
    }
  }

  // psi = U^dagger e_n => U[n][j] = (s.x, -s.y)
  #pragma unroll
  for (int k = 0; k < 4; ++k) {
    const int j = (wv << 8) | (k << 6) | lane;
    Wt[(size_t)(2 * n) * 1024 + j] = (_Float16)s[k].x;
    Wt[(size_t)(2 * n + 1) * 1024 + j] = (_Float16)(-s[k].y);
  }
}

// ---------------- LDS-staged GEMM ----------------
// Tile 128(M) x 128(N-rows, interleaved re/im = 64 js), BK=64, 13 K-steps
// (K=832 covers the 784 nonzero cols). 4 waves = 2(M) x 2(N), 64x64 each.
// LDS swizzle: row r's 8 16B-slots permuted s -> s^(r&7); staged with linear
// LDS dest + swizzled GLOBAL source; read with same XOR (rule #21).
#define GZ_NSTEP 13

__device__ __forceinline__ void stage_tiles(const _Float16* __restrict__ gA,
                                            const _Float16* __restrict__ gB,
                                            _Float16* sA, _Float16* sB,
                                            int k0, int wv, int lane) {
  const int rIn = lane >> 3;                    // row within chunk (0..7)
  const int colh = ((lane & 7) ^ rIn) * 8;      // swizzled source 16B-slot
  #pragma unroll
  for (int c = 0; c < 4; ++c) {
    const int chunk = wv * 4 + c;
    const size_t grow = (size_t)(chunk * 8 + rIn) * 1024 + k0 + colh;
    auto* la = (__attribute__((address_space(3))) void*)(sA + chunk * 512 + lane * 8);
    __builtin_amdgcn_global_load_lds(
        (const __attribute__((address_space(1))) void*)(gA + grow), la, 16, 0, 0);
    auto* lb = (__attribute__((address_space(3))) void*)(sB + chunk * 512 + lane * 8);
    __builtin_amdgcn_global_load_lds(
        (const __attribute__((address_space(1))) void*)(gB + grow), lb, 16, 0, 0);
  }
}

__device__ __forceinline__ int lds_off(int row, int slot) {
  return row * 64 + ((slot ^ (row & 7)) * 8);
}

__global__ __launch_bounds__(256) void gemm_z(const _Float16* __restrict__ Xh,
                                              const _Float16* __restrict__ Wt,
                                              float* __restrict__ part, int B) {
  __shared__ _Float16 smA[2][128 * 64];
  __shared__ _Float16 smB[2][128 * 64];

  const int tid = threadIdx.x;
  const int lane = tid & 63;
  const int wv = tid >> 6;
  const int wm = wv >> 1, wn = wv & 1;
  const int row0 = blockIdx.x * 128;
  const int n0 = blockIdx.y * 128;

  const _Float16* gA = Xh + (size_t)row0 * 1024;
  const _Float16* gB = Wt + (size_t)n0 * 1024;

  const int lr = lane & 15;
  const int lq = lane >> 4;       // 0..3: which 8-f16 K-slot within 32

  f32x4v acc[4][4];
  #pragma unroll
  for (int m = 0; m < 4; ++m)
    #pragma unroll
    for (int f = 0; f < 4; ++f) acc[m][f] = f32x4v{0.f, 0.f, 0.f, 0.f};

  stage_tiles(gA, gB, smA[0], smB[0], 0, wv, lane);
  __syncthreads();

  for (int t = 0; t < GZ_NSTEP; ++t) {
    const int cur = t & 1;
    if (t + 1 < GZ_NSTEP)
      stage_tiles(gA, gB, smA[cur ^ 1], smB[cur ^ 1], (t + 1) * 64, wv, lane);

    #pragma unroll
    for (int kk = 0; kk < 2; ++kk) {
      const int slot = kk * 4 + lq;
      f16x8 a[4], b[4];
      #pragma unroll
      for (int m = 0; m < 4; ++m) {
        const int row = wm * 64 + m * 16 + lr;
        a[m] = *reinterpret_cast<const f16x8*>(&smA[cur][lds_off(row, slot)]);
      }
      #pragma unroll
      for (int f = 0; f < 4; ++f) {
        const int row = wn * 64 + f * 16 + lr;
        b[f] = *reinterpret_cast<const f16x8*>(&smB[cur][lds_off(row, slot)]);
      }
      #pragma unroll
      for (int m = 0; m < 4; ++m)
        #pragma unroll
        for (int f = 0; f < 4; ++f)
          acc[m][f] = __builtin_amdgcn_mfma_f32_16x16x32_f16(a[m], b[f], acc[m][f], 0, 0, 0);
    }
    __syncthreads();
  }

  // Epilogue: sum of squares over the wave's 64 N-rows (= 32 js re/im pairs).
  const int pp = blockIdx.y * 2 + wn;
  #pragma unroll
  for (int m = 0; m < 4; ++m) {
    f32x4v p = f32x4v{0.f, 0.f, 0.f, 0.f};
    #pragma unroll
    for (int f = 0; f < 4; ++f) p += acc[m][f] * acc[m][f];
    #pragma unroll
    for (int msk = 1; msk < 16; msk <<= 1) {
      p.x += __shfl_xor(p.x, msk, 64);
      p.y += __shfl_xor(p.y, msk, 64);
      p.z += __shfl_xor(p.z, msk, 64);
      p.w += __shfl_xor(p.w, msk, 64);
    }
    if (lr == 0) {
      const int rbase = row0 + wm * 64 + m * 16 + lq * 4;
      float* dst = part + (size_t)pp * B + rbase;
      dst[0] = p.x; dst[1] = p.y; dst[2] = p.z; dst[3] = p.w;
    }
  }
}

// logits from 32 chunk partials: sign0 = bit9 -> pp&16, sign1 = bit8 -> pp&8.
__global__ __launch_bounds__(1024) void nll_mean(const float* __restrict__ part,
                                                 const int* __restrict__ y,
                                                 float* __restrict__ out, int B) {
  const int t = threadIdx.x;
  const int rpt = B / 1024;
  float s = 0.f;
  for (int rr = 0; rr < rpt; ++rr) {
    const int row = t + rr * 1024;
    float q0 = 0.f, q1 = 0.f, nn = 0.f;
    #pragma unroll
    for (int pp = 0; pp < 32; ++pp) {
      const float P = part[(size_t)pp * B + row];
      q0 += (pp & 16) ? -P : P;
      q1 += (pp & 8) ? -P : P;
      nn += P;
    }
    const float z0 = q0 / nn, z1 = q1 / nn;
    const float mx = fmaxf(z0, z1);
    const float lse = mx + logf(expf(z0 - mx) + expf(z1 - mx));
    const float ly = (y[row] == 0) ? z0 : z1;
    s += lse - ly;
  }
  #pragma unroll
  for (int msk = 1; msk < 64; msk <<= 1) s += __shfl_xor(s, msk, 64);
  __shared__ float red[16];
  if ((t & 63) == 0) red[t >> 6] = s;
  __syncthreads();
  if (t == 0) {
    float tot = 0.f;
    #pragma unroll
    for (int q = 0; q < 16; ++q) tot += red[q];
    out[0] = tot / (float)B;
  }
}

} // namespace

extern "C" void kernel_launch(void* const* d_in, const int* in_sizes, int n_in,
                              void* d_out, int out_size, void* d_ws, size_t ws_size,
                              hipStream_t stream) {
  const float* x  = (const float*)d_in[0];
  const int*   y  = (const int*)d_in[1];
  const float* w  = (const float*)d_in[2];
  const float* w1 = (const float*)d_in[3];
  const float* w2 = (const float*)d_in[4];
  float* out = (float*)d_out;

  const int B = in_sizes[0] / 784;      // 8192

  char* ws = (char*)d_ws;
  _Float16* Wt   = (_Float16*)ws;                                // 4 MB
  _Float16* Xh   = (_Float16*)(ws + (size_t)2048 * 1024 * 2);    // 16 MB
  float*    part = (float*)(ws + (size_t)2048 * 1024 * 2 + (size_t)B * 1024 * 2);

  qprep<<<1024 + (B * 128) / 256, 256, 0, stream>>>(w, w1, w2, x, Wt, Xh);
  gemm_z<<<dim3(B / 128, 16), 256, 0, stream>>>(Xh, Wt, part, B);
  nll_mean<<<1, 1024, 0, stream>>>(part, y, out, B);
}